// Round 14
// baseline (155.320 us; speedup 1.0000x reference)
//
#include <hip/hip_runtime.h>
#include <math.h>

#define A_N   8732
#define C_N   81
#define B_N   32
#define NCLS  80
#define NTASK (B_N * NCLS)
#define TOPK  100
#define NTHR  256
#define CAND  512
#define ACH   128                        // anchors per scatter chunk
#define NCH   ((A_N + ACH - 1) / ACH)    // 69
#define LCAP  16                         // LDS list slots per (block, task)
#define CPAD  16                         // gcount padding: 16 u32 = 64 B per task
#define THR_LOGIT (-0.8472978603872034)  // ln(3/7): sigmoid_f64(x)>0.3 <=> x>THR
#define XFIX  2.0f                       // fixed optimistic gather threshold

__device__ __forceinline__ unsigned mapf(float x) {
    unsigned b = __float_as_uint(x);
    return b ^ ((b & 0x80000000u) ? 0xFFFFFFFFu : 0x80000000u);
}
__device__ __forceinline__ float unmapf(unsigned u) {
    unsigned b = (u & 0x80000000u) ? (u ^ 0x80000000u) : ~u;
    return __uint_as_float(b);
}

// Exact f64 decode (reference op order) from raw regression/prior values.
__device__ __forceinline__ void dec64(const float4 r4, const float4 p4,
                                      double* bx, double* area) {
    double ty = (double)r4.x / 10.0, tx = (double)r4.y / 10.0;
    double th = (double)r4.z / 5.0,  tw = (double)r4.w / 5.0;
    double cy = ty * (double)p4.z + (double)p4.x;
    double cx = tx * (double)p4.w + (double)p4.y;
    double hh = exp(th) * (double)p4.z;
    double ww = exp(tw) * (double)p4.w;
    bx[0] = cy - hh / 2.0; bx[1] = cx - ww / 2.0;
    bx[2] = cy + hh / 2.0; bx[3] = cx + ww / 2.0;
    double e0 = bx[2] - bx[0]; if (e0 < 0.0) e0 = 0.0;
    double e1 = bx[3] - bx[1]; if (e1 < 0.0) e1 = 0.0;
    *area = e0 * e1;
}

// ---- Kernel S: contiguous slab read + LDS-aggregated candidate scatter ----
__global__ __launch_bounds__(NTHR) void scatter_cand_kernel(
    const float* __restrict__ logits,            // (B, A, 81)
    unsigned long long* __restrict__ gcand,      // (NTASK, CAND) full sort keys
    unsigned* __restrict__ gcountP)              // (NTASK * CPAD) padded counters
{
    __shared__ unsigned long long llist[NCLS * LCAP];   // 10 KB
    __shared__ unsigned lcnt[NCLS];
    __shared__ unsigned sbase[NCLS];

    const int b  = blockIdx.x / NCH;
    const int ck = blockIdx.x % NCH;
    const int a0 = ck * ACH;
    const int an = min(ACH, A_N - a0);
    const int tid = threadIdx.x;

    for (int i = tid; i < NCLS; i += NTHR) lcnt[i] = 0;
    __syncthreads();

    const size_t E0 = (size_t)C_N * ((size_t)b * A_N + a0);
    const unsigned NE = (unsigned)(an * C_N);
    const size_t F0 = E0 >> 2;
    const size_t F1 = (E0 + NE + 3) >> 2;
    const float4* src4 = (const float4*)logits;

    for (size_t f = F0 + tid; f < F1; f += NTHR) {
        float4 v = src4[f];
        // fast path: ~91% of quads have no candidate at all
        float mx = fmaxf(fmaxf(v.x, v.y), fmaxf(v.z, v.w));
        if (mx < XFIX) continue;
        size_t e = f * 4;
        float xs[4] = { v.x, v.y, v.z, v.w };
        #pragma unroll
        for (int k = 0; k < 4; ++k, ++e) {
            if (e >= E0 && e < E0 + NE && xs[k] >= XFIX) {
                unsigned rel = (unsigned)(e - E0);
                unsigned ar = rel / (unsigned)C_N;          // const-div (magic mul)
                unsigned ch = rel - ar * (unsigned)C_N;
                if (ch > 0) {
                    int t = (int)ch - 1;
                    unsigned a = (unsigned)a0 + ar;
                    unsigned long long key =
                        ((unsigned long long)mapf(xs[k]) << 32) | (unsigned)(~a);
                    unsigned pos = atomicAdd(&lcnt[t], 1u);
                    if (pos < LCAP) {
                        llist[t * LCAP + pos] = key;
                    } else {                                 // ~never: direct append
                        int task = b * NCLS + t;
                        unsigned p = atomicAdd(&gcountP[task * CPAD], 1u);
                        if (p < CAND) gcand[(size_t)task * CAND + p] = key;
                    }
                }
            }
        }
    }
    __syncthreads();

    if (tid < NCLS) {
        unsigned n = lcnt[tid]; if (n > LCAP) n = LCAP;
        sbase[tid] = n ? atomicAdd(&gcountP[(b * NCLS + tid) * CPAD], n) : 0u;
        lcnt[tid] = n;
    }
    __syncthreads();

    for (int i = tid; i < NCLS * LCAP; i += NTHR) {
        int t = i >> 4, s = i & (LCAP - 1);
        if ((unsigned)s < lcnt[t]) {
            unsigned dst = sbase[t] + (unsigned)s;
            if (dst < CAND)
                gcand[(size_t)(b * NCLS + t) * CAND + dst] = llist[i];
        }
    }
}

// ---- Kernel W4: 4 waves per block, ONE TASK PER WAVE, zero barriers ----
__global__ __launch_bounds__(NTHR) void ssd_nms_wave4(
    const float* __restrict__ logits,
    const unsigned long long* __restrict__ gcand,
    const unsigned* __restrict__ gcountP,
    const float* __restrict__ boxreg,
    const float* __restrict__ priors,
    float* __restrict__ out)
{
    __shared__ unsigned long long candL[4][CAND];   // 16384 B
    __shared__ unsigned long long sselL[4][TOPK];   //  3200 B
    __shared__ double sbL[4][4][TOPK];              // 12800 B
    __shared__ double saL[4][TOPK];                 //  3200 B
    __shared__ float4 fbL[4][TOPK];                 //  6400 B
    __shared__ float  faL[4][TOPK];                 //  1600 B

    const int w = threadIdx.x >> 6;
    const int l = threadIdx.x & 63;
    const int task = blockIdx.x * 4 + w;
    const int b = task / NCLS;
    const int c = task % NCLS;
    const float* lg = logits + ((size_t)b * A_N * C_N) + (c + 1);

    sselL[w][l] = 0ull;
    if (l < TOPK - 64) sselL[w][64 + l] = 0ull;

    int M = 0;
    const int count = (int)gcountP[task * CPAD];
    if (count >= TOPK && count <= CAND) {
        // ---- optimistic: keys preassembled, contiguous load
        M = count;
        const unsigned long long* lst = gcand + (size_t)task * CAND;
        #pragma unroll
        for (int k = 0; k < CAND / 64; ++k) {
            int idx = l + k * 64;
            if (idx < M) candL[w][idx] = lst[idx];
        }
    } else {
        // ---- degenerate (never on bench data): exact in-wave cutoff search
        unsigned cut = 1u;
        {
            // count valid at a given cutoff
            int nv = 0;
            for (int a = l; a < A_N; a += 64) {
                float x = lg[(size_t)a * C_N];
                if ((double)x > THR_LOGIT) nv++;
            }
            #pragma unroll
            for (int off = 32; off; off >>= 1) nv += __shfl_down(nv, off);
            nv = __shfl(nv, 0);
            if (nv > CAND) {
                unsigned lo = 1u, hi = 0xFFFFFFFFu;
                for (int it = 0; it < 34; ++it) {
                    unsigned mid = lo + ((hi - lo) >> 1);
                    if (mid == lo) break;
                    int cm = 0;
                    for (int a = l; a < A_N; a += 64) {
                        float x = lg[(size_t)a * C_N];
                        if ((double)x > THR_LOGIT && mapf(x) >= mid) cm++;
                    }
                    #pragma unroll
                    for (int off = 32; off; off >>= 1) cm += __shfl_down(cm, off);
                    cm = __shfl(cm, 0);
                    if (cm >= TOPK) lo = mid; else hi = mid;
                }
                cut = lo;
            }
        }
        int cnt2 = 0;
        for (int a0i = 0; a0i < A_N; a0i += 64) {
            int a = a0i + l;
            bool pr = false; unsigned long long key = 0ull;
            if (a < A_N) {
                float x = lg[(size_t)a * C_N];
                if ((double)x > THR_LOGIT) {
                    unsigned u = mapf(x);
                    if (u >= cut) {
                        pr = true;
                        key = ((unsigned long long)u << 32) | (unsigned)(~(unsigned)a);
                    }
                }
            }
            unsigned long long mk = __ballot(pr);
            if (pr) {
                int pos = cnt2 + (int)__popcll(mk & ((1ull << l) - 1ull));
                if (pos < CAND) candL[w][pos] = key;
            }
            cnt2 += (int)__popcll(mk);
        }
        M = min(cnt2, CAND);
    }
    const int Mr = (M + 3) & ~3;
    for (int idx = M + l; idx < Mr; idx += 64) candL[w][idx] = 0ull;

    // ---- all-pairs rank: lane keys in regs, broadcast LDS reads
    unsigned long long myk[CAND / 64];
    int rk[CAND / 64];
    const int Kr = (Mr + 63) >> 6;
    #pragma unroll
    for (int k = 0; k < CAND / 64; ++k) {
        int idx = l + k * 64;
        myk[k] = (idx < Mr) ? candL[w][idx] : 0ull;
        rk[k] = 0;
    }
    for (int j = 0; j < Mr; j += 4) {
        unsigned long long c0 = candL[w][j + 0];
        unsigned long long c1 = candL[w][j + 1];
        unsigned long long c2 = candL[w][j + 2];
        unsigned long long c3 = candL[w][j + 3];
        for (int k = 0; k < Kr; ++k) {
            rk[k] += (c0 > myk[k]) ? 1 : 0;
            rk[k] += (c1 > myk[k]) ? 1 : 0;
            rk[k] += (c2 > myk[k]) ? 1 : 0;
            rk[k] += (c3 > myk[k]) ? 1 : 0;
        }
    }
    #pragma unroll
    for (int k = 0; k < CAND / 64; ++k)
        if (myk[k] != 0ull && rk[k] < TOPK) sselL[w][rk[k]] = myk[k];

    // ---- decode: lane owns slots l and 64+l; f64 once per box -> LDS
    unsigned long long keyA = sselL[w][l];
    unsigned long long keyB = (l < TOPK - 64) ? sselL[w][64 + l] : 0ull;
    float A0 = 0, A1 = 0, A2 = 0, A3 = 0, arA = 0, scA = 0;
    float B0 = 0, B1 = 0, B2 = 0, B3 = 0, arB = 0, scB = 0;
    {
        double bx[4] = {0.0, 0.0, 0.0, 0.0}, ar = 0.0;
        if (keyA) {
            int a = (int)(~(unsigned)keyA);
            float x = unmapf((unsigned)(keyA >> 32));
            scA = 1.0f / (1.0f + __expf(-x));
            float4 r4 = *(const float4*)(boxreg + ((size_t)b * A_N + a) * 4);
            float4 p4 = *(const float4*)(priors + (size_t)a * 4);
            dec64(r4, p4, bx, &ar);
        }
        sbL[w][0][l] = bx[0]; sbL[w][1][l] = bx[1];
        sbL[w][2][l] = bx[2]; sbL[w][3][l] = bx[3];
        saL[w][l] = ar;
        A0 = (float)bx[0]; A1 = (float)bx[1]; A2 = (float)bx[2]; A3 = (float)bx[3];
        arA = (float)ar;
        fbL[w][l] = make_float4(A0, A1, A2, A3); faL[w][l] = arA;
    }
    if (l < TOPK - 64) {
        double bx[4] = {0.0, 0.0, 0.0, 0.0}, ar = 0.0;
        if (keyB) {
            int a = (int)(~(unsigned)keyB);
            float x = unmapf((unsigned)(keyB >> 32));
            scB = 1.0f / (1.0f + __expf(-x));
            float4 r4 = *(const float4*)(boxreg + ((size_t)b * A_N + a) * 4);
            float4 p4 = *(const float4*)(priors + (size_t)a * 4);
            dec64(r4, p4, bx, &ar);
        }
        sbL[w][0][64 + l] = bx[0]; sbL[w][1][64 + l] = bx[1];
        sbL[w][2][64 + l] = bx[2]; sbL[w][3][64 + l] = bx[3];
        saL[w][64 + l] = ar;
        B0 = (float)bx[0]; B1 = (float)bx[1]; B2 = (float)bx[2]; B3 = (float)bx[3];
        arB = (float)ar;
        fbL[w][64 + l] = make_float4(B0, B1, B2, B3); faL[w][64 + l] = arB;
    }
    const unsigned long long v0 = __ballot(keyA != 0ull);
    const unsigned long long v1 = __ballot((l < TOPK - 64) && keyB != 0ull);

    // ---- suppression rows in registers: lane l -> rows l and 99-l (l<50)
    auto pairSup = [&](float i0, float i1, float i2, float i3, float ia,
                       int irow, int j) -> bool {
        float4 bj = fbL[w][j]; float aj = faL[w][j];
        float tl0 = fmaxf(i0, bj.x), tl1 = fmaxf(i1, bj.y);
        float br0 = fminf(i2, bj.z), br1 = fminf(i3, bj.w);
        float wh0 = fmaxf(br0 - tl0, 0.f), wh1 = fmaxf(br1 - tl1, 0.f);
        float inter = wh0 * wh1;
        float denom = (ia + aj) - inter;
        bool sup = inter > 0.6004f * denom;
        bool amb = !sup && (inter > 0.5996f * denom) && (inter > 0.f);
        if (amb) {   // rare; cheap: f64 boxes already in LDS
            double tl0d = fmax(sbL[w][0][irow], sbL[w][0][j]);
            double tl1d = fmax(sbL[w][1][irow], sbL[w][1][j]);
            double br0d = fmin(sbL[w][2][irow], sbL[w][2][j]);
            double br1d = fmin(sbL[w][3][irow], sbL[w][3][j]);
            double wh0d = br0d - tl0d; if (wh0d < 0.0) wh0d = 0.0;
            double wh1d = br1d - tl1d; if (wh1d < 0.0) wh1d = 0.0;
            double interd = wh0d * wh1d;
            sup = interd > 0.6 * (((saL[w][irow] + saL[w][j]) - interd) + 1e-9);
        }
        return sup;
    };

    unsigned long long mA0 = 0, mA1 = 0, mB0 = 0, mB1 = 0;
    if (l < 50) {
        for (int j = l + 1; j < TOPK; ++j)
            if (pairSup(A0, A1, A2, A3, arA, l, j)) {
                if (j < 64) mA0 |= 1ull << j; else mA1 |= 1ull << (j - 64);
            }
        int rB = 99 - l;
        float4 bi = fbL[w][rB]; float ai = faL[w][rB];
        for (int j = rB + 1; j < TOPK; ++j)
            if (pairSup(bi.x, bi.y, bi.z, bi.w, ai, rB, j)) {
                if (j < 64) mB0 |= 1ull << j; else mB1 |= 1ull << (j - 64);
            }
    }

    // ---- greedy scan fully in registers via shfl broadcast
    unsigned long long kp0 = ~0ull, kp1 = (1ull << (TOPK - 64)) - 1ull;
    for (int i = 0; i < TOPK; ++i) {
        bool low = (i < 50);
        int src = low ? i : 99 - i;
        unsigned long long m0 = low ? __shfl(mA0, src) : __shfl(mB0, src);
        unsigned long long m1 = low ? __shfl(mA1, src) : __shfl(mB1, src);
        bool kb = (i < 64) ? ((kp0 >> i) & 1ull) : ((kp1 >> (i - 64)) & 1ull);
        bool vb = (i < 64) ? ((v0 >> i) & 1ull) : ((v1 >> (i - 64)) & 1ull);
        if (kb && vb) { kp0 &= ~m0; kp1 &= ~m1; }
    }

    // ---- write from registers
    {
        bool keepA = ((kp0 >> l) & 1ull) && (keyA != 0ull);
        size_t baseA = ((size_t)task * TOPK + l) * 5;
        out[baseA + 0] = keepA ? A0 : 0.0f;
        out[baseA + 1] = keepA ? A1 : 0.0f;
        out[baseA + 2] = keepA ? A2 : 0.0f;
        out[baseA + 3] = keepA ? A3 : 0.0f;
        out[baseA + 4] = keepA ? scA : 0.0f;
        if (l < TOPK - 64) {
            bool keepB = ((kp1 >> l) & 1ull) && (keyB != 0ull);
            size_t baseB = ((size_t)task * TOPK + 64 + l) * 5;
            out[baseB + 0] = keepB ? B0 : 0.0f;
            out[baseB + 1] = keepB ? B1 : 0.0f;
            out[baseB + 2] = keepB ? B2 : 0.0f;
            out[baseB + 3] = keepB ? B3 : 0.0f;
            out[baseB + 4] = keepB ? scB : 0.0f;
        }
    }
}

// ---- Standalone fallback (ws too small): validated R13 path ----
__global__ __launch_bounds__(NTHR) void ssd_nms_fallback(
    const float* __restrict__ logits,
    const float* __restrict__ boxreg,
    const float* __restrict__ priors,
    float* __restrict__ out)
{
    const int task = blockIdx.x;
    const int b = task / NCLS;
    const int c = task % NCLS;
    const int tid = threadIdx.x;

    __shared__ unsigned hist[2048];
    __shared__ unsigned wt4[4];
    __shared__ unsigned long long cand[CAND];
    __shared__ unsigned long long ssel[TOPK];
    __shared__ double sb0[TOPK], sb1[TOPK], sb2[TOPK], sb3[TOPK], sarea[TOPK];
    __shared__ float fb0[TOPK], fb1[TOPK], fb2[TOPK], fb3[TOPK];
    __shared__ float farea[TOPK], fscore[TOPK];
    __shared__ int svalid[TOPK];
    __shared__ unsigned long long supmask[TOPK][2];
    __shared__ unsigned long long keepw[2];
    __shared__ int scal[2];

    const float* lg = logits + ((size_t)b * A_N * C_N) + (c + 1);

    for (int k = tid; k < 2048; k += NTHR) hist[k] = 0;
    for (int i = tid; i < CAND; i += NTHR) cand[i] = 0ull;
    if (tid < TOPK) ssel[tid] = 0ull;
    if (tid == 0) { scal[0] = 0; scal[1] = 1; }
    __syncthreads();

    for (int a = tid; a < A_N; a += NTHR) {
        float x = lg[(size_t)a * C_N];
        if ((double)x > THR_LOGIT) atomicAdd(&hist[mapf(x) >> 21], 1u);
    }
    __syncthreads();
    {
        unsigned s = 0;
        #pragma unroll
        for (int k = 0; k < 8; ++k) s += hist[tid * 8 + k];
        unsigned incl = s;
        int lane = tid & 63;
        #pragma unroll
        for (int off = 1; off < 64; off <<= 1) {
            unsigned v = __shfl_down(incl, off);
            if (lane + off < 64) incl += v;
        }
        if (lane == 0) wt4[tid >> 6] = incl;
        __syncthreads();
        unsigned hi = 0;
        #pragma unroll
        for (int w = 0; w < 4; ++w) if (w > (tid >> 6)) hi += wt4[w];
        unsigned excl = hi + (incl - s);
        if (excl < TOPK && excl + s >= TOPK) {
            unsigned running = excl;
            #pragma unroll
            for (int k = 7; k >= 0; --k) {
                running += hist[tid * 8 + k];
                if (running >= TOPK) { scal[1] = (int)(((unsigned)(tid * 8 + k)) << 21); break; }
            }
        }
    }
    __syncthreads();
    const unsigned cutoff = (unsigned)scal[1];

    for (int a = tid; a < A_N; a += NTHR) {
        float x = lg[(size_t)a * C_N];
        if ((double)x > THR_LOGIT) {
            unsigned u = mapf(x);
            if (u >= cutoff) {
                int p = atomicAdd(&scal[0], 1);
                if (p < CAND) cand[p] = ((unsigned long long)u << 32) | (unsigned)(~(unsigned)a);
            }
        }
    }
    __syncthreads();
    const int M = min(scal[0], CAND);
    {
        int Mr = (M + 7) & ~7;
        for (int i = tid; i < Mr; i += NTHR) {
            unsigned long long mykey = cand[i];
            int rank = 0;
            for (int j = 0; j < Mr; ++j) rank += (cand[j] > mykey) ? 1 : 0;
            if (mykey != 0ull && rank < TOPK) ssel[rank] = mykey;
        }
    }
    __syncthreads();
    if (tid < TOPK) {
        unsigned long long key = ssel[tid];
        int valid = (key != 0ull);
        double bx[4] = {0.0, 0.0, 0.0, 0.0}, ar = 0.0;
        float sc = 0.f;
        if (valid) {
            int a = (int)(~(unsigned)key);
            float x = unmapf((unsigned)(key >> 32));
            sc = 1.0f / (1.0f + __expf(-x));
            float4 r4 = *(const float4*)(boxreg + ((size_t)b * A_N + a) * 4);
            float4 p4 = *(const float4*)(priors + (size_t)a * 4);
            dec64(r4, p4, bx, &ar);
        }
        sb0[tid] = bx[0]; sb1[tid] = bx[1]; sb2[tid] = bx[2]; sb3[tid] = bx[3];
        sarea[tid] = ar;
        fb0[tid] = (float)bx[0]; fb1[tid] = (float)bx[1];
        fb2[tid] = (float)bx[2]; fb3[tid] = (float)bx[3];
        farea[tid] = (float)ar; fscore[tid] = sc; svalid[tid] = valid;
    }
    __syncthreads();
    if (tid < 2 * TOPK) {
        int i = tid >> 1, w = tid & 1;
        unsigned long long m = 0;
        if (svalid[i]) {
            float i0=fb0[i], i1=fb1[i], i2=fb2[i], i3=fb3[i], ia=farea[i];
            int jbase = w * 64, jend = min(jbase + 64, TOPK);
            int jstart = (jbase > i + 1) ? jbase : (i + 1);
            for (int j = jstart; j < jend; ++j) {
                float tl0=fmaxf(i0,fb0[j]), tl1=fmaxf(i1,fb1[j]);
                float br0=fminf(i2,fb2[j]), br1=fminf(i3,fb3[j]);
                float wh0=fmaxf(br0-tl0,0.f), wh1=fmaxf(br1-tl1,0.f);
                float inter=wh0*wh1, denom=(ia+farea[j])-inter;
                bool sup = inter > 0.6004f*denom;
                bool amb = !sup && (inter > 0.5996f*denom) && (inter > 0.f);
                if (amb) {
                    double tl0d = fmax(sb0[i], sb0[j]);
                    double tl1d = fmax(sb1[i], sb1[j]);
                    double br0d = fmin(sb2[i], sb2[j]);
                    double br1d = fmin(sb3[i], sb3[j]);
                    double wh0d = br0d - tl0d; if (wh0d < 0.0) wh0d = 0.0;
                    double wh1d = br1d - tl1d; if (wh1d < 0.0) wh1d = 0.0;
                    double interd = wh0d * wh1d;
                    sup = interd > 0.6 * (((sarea[i] + sarea[j]) - interd) + 1e-9);
                }
                if (sup) m |= 1ull << (j - jbase);
            }
        }
        supmask[i][w] = m;
    }
    __syncthreads();
    if (tid == 0) {
        unsigned long long kp0 = ~0ull, kp1 = ~0ull;
        for (int i = 0; i < TOPK; ++i) {
            bool kb = (i < 64) ? ((kp0 >> i) & 1ull) : ((kp1 >> (i - 64)) & 1ull);
            if (kb && svalid[i]) { kp0 &= ~supmask[i][0]; kp1 &= ~supmask[i][1]; }
        }
        keepw[0] = kp0; keepw[1] = kp1;
    }
    __syncthreads();
    if (tid < TOPK) {
        bool kb = (tid < 64) ? ((keepw[0] >> tid) & 1ull)
                             : ((keepw[1] >> (tid - 64)) & 1ull);
        bool kp = kb && (svalid[tid] != 0);
        size_t base = ((size_t)task * TOPK + tid) * 5;
        out[base + 0] = kp ? fb0[tid] : 0.0f;
        out[base + 1] = kp ? fb1[tid] : 0.0f;
        out[base + 2] = kp ? fb2[tid] : 0.0f;
        out[base + 3] = kp ? fb3[tid] : 0.0f;
        out[base + 4] = kp ? fscore[tid] : 0.0f;
    }
}

extern "C" void kernel_launch(void* const* d_in, const int* in_sizes, int n_in,
                              void* d_out, int out_size, void* d_ws, size_t ws_size,
                              hipStream_t stream) {
    const float* logits = (const float*)d_in[0];
    const float* boxreg = (const float*)d_in[1];
    const float* priors = (const float*)d_in[2];
    float* out = (float*)d_out;

    const size_t cand_bytes  = (size_t)NTASK * CAND * sizeof(unsigned long long); // 10.49 MB
    const size_t count_bytes = (size_t)NTASK * CPAD * sizeof(unsigned);           // 160 KB
    if (ws_size >= cand_bytes + count_bytes) {
        unsigned long long* gcand = (unsigned long long*)d_ws;
        unsigned* gcountP = (unsigned*)((char*)d_ws + cand_bytes);
        hipMemsetAsync(gcountP, 0, count_bytes, stream);
        scatter_cand_kernel<<<dim3(B_N * NCH), dim3(NTHR), 0, stream>>>(
            logits, gcand, gcountP);
        ssd_nms_wave4<<<dim3(NTASK / 4), dim3(NTHR), 0, stream>>>(
            logits, gcand, gcountP, boxreg, priors, out);
    } else {
        ssd_nms_fallback<<<dim3(NTASK), dim3(NTHR), 0, stream>>>(
            logits, boxreg, priors, out);
    }
}

// Round 15
// 99.212 us; speedup vs baseline: 1.5655x; 1.5655x over previous
//
#include <hip/hip_runtime.h>
#include <math.h>

#define A_N   8732
#define C_N   81
#define B_N   32
#define NCLS  80
#define NTASK (B_N * NCLS)
#define TOPK  100
#define NTHR  256
#define CAND  512
#define ACH   128                        // anchors per scatter chunk
#define NCH   ((A_N + ACH - 1) / ACH)    // 69
#define LCAP  16                         // LDS list slots per (block, task)
#define CPAD  16                         // gcount padding: 16 u32 = 64 B per task
#define THR_LOGIT (-0.8472978603872034)  // ln(3/7): sigmoid_f64(x)>0.3 <=> x>THR
#define XFIX  2.0f                       // fixed optimistic gather threshold

// ---- LDS layout for main kernel (byte offsets, disjoint lifetimes overlaid)
#define OFF_SB0    0        // double[100] -> 800   (overlays hist, post-rank)
#define OFF_SB1    800
#define OFF_SB2    1600
#define OFF_SB3    2400
#define OFF_SAREA  3200     // -> 4000
#define OFF_KEEPW  4000     // u64[2] -> 4016
#define OFF_HIST   0        // unsigned[2048] -> 8192 (fallback path only)
#define OFF_CAND   8192     // u64[512] -> 12288 (dead after rank/sort copy)
#define OFF_FB0    8192     // float[100] (overlays cand, post-rank)
#define OFF_FB1    8592
#define OFF_FB2    8992
#define OFF_FB3    9392
#define OFF_FAREA  9792
#define OFF_FSC    10192
#define OFF_SVAL   10592    // int[100] -> 10992
#define OFF_SSEL   12288    // u64[100] -> 13088
#define OFF_SUP    13088    // u64[100][2] -> 14688
#define OFF_WT4    14688
#define OFF_SCAL   14704    // -> 14712
#define SMEM_SZ    14720

__device__ __forceinline__ unsigned mapf(float x) {
    unsigned b = __float_as_uint(x);
    return b ^ ((b & 0x80000000u) ? 0xFFFFFFFFu : 0x80000000u);
}
__device__ __forceinline__ float unmapf(unsigned u) {
    unsigned b = (u & 0x80000000u) ? (u ^ 0x80000000u) : ~u;
    return __uint_as_float(b);
}

// Exact f64 decode (reference op order) from raw regression/prior values.
__device__ __forceinline__ void dec64(const float4 r4, const float4 p4,
                                      double* bx, double* area) {
    double ty = (double)r4.x / 10.0, tx = (double)r4.y / 10.0;
    double th = (double)r4.z / 5.0,  tw = (double)r4.w / 5.0;
    double cy = ty * (double)p4.z + (double)p4.x;
    double cx = tx * (double)p4.w + (double)p4.y;
    double hh = exp(th) * (double)p4.z;
    double ww = exp(tw) * (double)p4.w;
    bx[0] = cy - hh / 2.0; bx[1] = cx - ww / 2.0;
    bx[2] = cy + hh / 2.0; bx[3] = cx + ww / 2.0;
    double e0 = bx[2] - bx[0]; if (e0 < 0.0) e0 = 0.0;
    double e1 = bx[3] - bx[1]; if (e1 < 0.0) e1 = 0.0;
    *area = e0 * e1;
}

// ---- Kernel S: contiguous slab read + LDS-aggregated candidate scatter ----
__global__ __launch_bounds__(NTHR) void scatter_cand_kernel(
    const float* __restrict__ logits,            // (B, A, 81)
    unsigned long long* __restrict__ gcand,      // (NTASK, CAND) full sort keys
    unsigned* __restrict__ gcountP)              // (NTASK * CPAD) padded counters
{
    __shared__ unsigned long long llist[NCLS * LCAP];   // 10 KB
    __shared__ unsigned lcnt[NCLS];
    __shared__ unsigned sbase[NCLS];

    const int b  = blockIdx.x / NCH;
    const int ck = blockIdx.x % NCH;
    const int a0 = ck * ACH;
    const int an = min(ACH, A_N - a0);
    const int tid = threadIdx.x;

    for (int i = tid; i < NCLS; i += NTHR) lcnt[i] = 0;
    __syncthreads();

    const size_t E0 = (size_t)C_N * ((size_t)b * A_N + a0);
    const unsigned NE = (unsigned)(an * C_N);
    const size_t F0 = E0 >> 2;
    const size_t F1 = (E0 + NE + 3) >> 2;
    const float4* src4 = (const float4*)logits;

    for (size_t f = F0 + tid; f < F1; f += NTHR) {
        float4 v = src4[f];
        size_t e = f * 4;
        float xs[4] = { v.x, v.y, v.z, v.w };
        #pragma unroll
        for (int k = 0; k < 4; ++k, ++e) {
            if (e >= E0 && e < E0 + NE && xs[k] >= XFIX) {
                unsigned rel = (unsigned)(e - E0);
                unsigned ar = rel / (unsigned)C_N;          // const-div (magic mul)
                unsigned ch = rel - ar * (unsigned)C_N;
                if (ch > 0) {
                    int t = (int)ch - 1;
                    unsigned a = (unsigned)a0 + ar;
                    unsigned long long key =
                        ((unsigned long long)mapf(xs[k]) << 32) | (unsigned)(~a);
                    unsigned pos = atomicAdd(&lcnt[t], 1u);
                    if (pos < LCAP) {
                        llist[t * LCAP + pos] = key;
                    } else {                                 // ~never: direct append
                        int task = b * NCLS + t;
                        unsigned p = atomicAdd(&gcountP[task * CPAD], 1u);
                        if (p < CAND) gcand[(size_t)task * CAND + p] = key;
                    }
                }
            }
        }
    }
    __syncthreads();

    if (tid < NCLS) {
        unsigned n = lcnt[tid]; if (n > LCAP) n = LCAP;
        sbase[tid] = n ? atomicAdd(&gcountP[(b * NCLS + tid) * CPAD], n) : 0u;
        lcnt[tid] = n;
    }
    __syncthreads();

    for (int i = tid; i < NCLS * LCAP; i += NTHR) {
        int t = i >> 4, s = i & (LCAP - 1);
        if ((unsigned)s < lcnt[t]) {
            unsigned dst = sbase[t] + (unsigned)s;
            if (dst < CAND)
                gcand[(size_t)(b * NCLS + t) * CAND + dst] = llist[i];
        }
    }
}

// ---- Kernel M: one task per block; bitonic top-100; shfl greedy scan ----
__global__ __launch_bounds__(NTHR) void ssd_nms_kernel(
    const float* __restrict__ logits,
    const unsigned long long* __restrict__ gcand,
    const unsigned* __restrict__ gcountP,
    const float* __restrict__ boxreg,
    const float* __restrict__ priors,
    float* __restrict__ out)
{
    const int task = blockIdx.x;
    const int b = task / NCLS;
    const int c = task % NCLS;
    const int tid = threadIdx.x;

    __shared__ __align__(16) char smem[SMEM_SZ];
    unsigned* hist = (unsigned*)(smem + OFF_HIST);
    unsigned long long* cand = (unsigned long long*)(smem + OFF_CAND);
    unsigned long long* ssel = (unsigned long long*)(smem + OFF_SSEL);
    unsigned* wt4 = (unsigned*)(smem + OFF_WT4);
    int* scal = (int*)(smem + OFF_SCAL);
    double* sb0 = (double*)(smem + OFF_SB0);
    double* sb1 = (double*)(smem + OFF_SB1);
    double* sb2 = (double*)(smem + OFF_SB2);
    double* sb3 = (double*)(smem + OFF_SB3);
    double* sarea = (double*)(smem + OFF_SAREA);
    float* fb0 = (float*)(smem + OFF_FB0);
    float* fb1 = (float*)(smem + OFF_FB1);
    float* fb2 = (float*)(smem + OFF_FB2);
    float* fb3 = (float*)(smem + OFF_FB3);
    float* farea = (float*)(smem + OFF_FAREA);
    float* fscore = (float*)(smem + OFF_FSC);
    int* svalid = (int*)(smem + OFF_SVAL);
    unsigned long long (*supmask)[2] = (unsigned long long (*)[2])(smem + OFF_SUP);
    unsigned long long* keepw = (unsigned long long*)(smem + OFF_KEEPW);

    const float* lg = logits + ((size_t)b * A_N * C_N) + (c + 1);

    // ---- issue candidate + count loads together (independent, overlap latency)
    const unsigned long long* lst = gcand + (size_t)task * CAND;
    unsigned long long pre0 = lst[tid];
    unsigned long long pre1 = lst[tid + NTHR];
    const int count = (int)gcountP[task * CPAD];

    if (tid < TOPK) ssel[tid] = 0ull;
    if (tid == 0) { scal[0] = 0; scal[1] = 1; }

    const bool optim = (count >= TOPK && count <= CAND);
    const bool useSort = optim && (count <= 256);
    int M;
    if (optim) {
        M = count;
        if (useSort) {
            cand[tid] = (tid < M) ? pre0 : 0ull;        // slots 0..255, zero-padded
        } else {
            if (tid < M) cand[tid] = pre0;
            if (tid + NTHR < M) cand[tid + NTHR] = pre1;
            int Mr = (M + 7) & ~7;
            for (int i = M + tid; i < Mr; i += NTHR) cand[i] = 0ull;
        }
    } else {
        // ---- fallback: full strided scan (rare / degenerate data)
        for (int k = tid; k < 2048; k += NTHR) hist[k] = 0;
        __syncthreads();
        for (int a = tid; a < A_N; a += NTHR) {
            float x = lg[(size_t)a * C_N];
            if ((double)x > THR_LOGIT) atomicAdd(&hist[mapf(x) >> 21], 1u);
        }
        __syncthreads();
        {
            unsigned s = 0;
            #pragma unroll
            for (int k = 0; k < 8; ++k) s += hist[tid * 8 + k];
            unsigned incl = s;
            int lane = tid & 63;
            #pragma unroll
            for (int off = 1; off < 64; off <<= 1) {
                unsigned v = __shfl_down(incl, off);
                if (lane + off < 64) incl += v;
            }
            if (lane == 0) wt4[tid >> 6] = incl;
            __syncthreads();
            unsigned hi = 0;
            #pragma unroll
            for (int w = 0; w < 4; ++w) if (w > (tid >> 6)) hi += wt4[w];
            unsigned excl = hi + (incl - s);
            if (excl < TOPK && excl + s >= TOPK) {
                unsigned running = excl;
                #pragma unroll
                for (int k = 7; k >= 0; --k) {
                    running += hist[tid * 8 + k];
                    if (running >= TOPK) { scal[1] = (int)(((unsigned)(tid * 8 + k)) << 21); break; }
                }
            }
        }
        __syncthreads();
        const unsigned cutoff = (unsigned)scal[1];
        for (int a = tid; a < A_N; a += NTHR) {
            float x = lg[(size_t)a * C_N];
            if ((double)x > THR_LOGIT) {
                unsigned u = mapf(x);
                if (u >= cutoff) {
                    int p = atomicAdd(&scal[0], 1);
                    if (p < CAND) cand[p] = ((unsigned long long)u << 32) | (unsigned)(~(unsigned)a);
                }
            }
        }
        __syncthreads();
        M = min(scal[0], CAND);
        int Mr = (M + 7) & ~7;
        for (int i = M + tid; i < Mr; i += NTHR) cand[i] = 0ull;
    }
    __syncthreads();

    if (useSort) {
        // ---- bitonic sort of 256 slots, descending; top-100 = slots 0..99
        for (int k2 = 2; k2 <= 256; k2 <<= 1) {
            for (int j = k2 >> 1; j > 0; j >>= 1) {
                int t = tid;
                int ixj = t ^ j;
                if (ixj > t) {
                    unsigned long long x0 = cand[t], x1 = cand[ixj];
                    bool descSeg = ((t & k2) == 0);
                    bool sw = descSeg ? (x0 < x1) : (x0 > x1);
                    if (sw) { cand[t] = x1; cand[ixj] = x0; }
                }
                __syncthreads();
            }
        }
        if (tid < TOPK) ssel[tid] = cand[tid];
    } else {
        // ---- exact rank via all-pairs (order-independent, LDS broadcast reads)
        int Mr = (M + 7) & ~7;
        for (int i = tid; i < Mr; i += NTHR) {
            unsigned long long mykey = cand[i];
            int rank = 0;
            #pragma unroll 8
            for (int j = 0; j < Mr; ++j) rank += (cand[j] > mykey) ? 1 : 0;
            if (mykey != 0ull && rank < TOPK) ssel[rank] = mykey;
        }
    }
    __syncthreads();

    // ---- decode top-100: f64 ONCE per box -> LDS; f32 shadows are casts
    if (tid < TOPK) {
        unsigned long long key = ssel[tid];
        int valid = (key != 0ull);
        double bx[4] = {0.0, 0.0, 0.0, 0.0}, ar = 0.0;
        float sc = 0.f;
        if (valid) {
            int a = (int)(~(unsigned)key);
            float x = unmapf((unsigned)(key >> 32));
            sc = 1.0f / (1.0f + __expf(-x));
            float4 r4 = *(const float4*)(boxreg + ((size_t)b * A_N + a) * 4);
            float4 p4 = *(const float4*)(priors + (size_t)a * 4);
            dec64(r4, p4, bx, &ar);
        }
        sb0[tid] = bx[0]; sb1[tid] = bx[1]; sb2[tid] = bx[2]; sb3[tid] = bx[3];
        sarea[tid] = ar;
        fb0[tid] = (float)bx[0]; fb1[tid] = (float)bx[1];
        fb2[tid] = (float)bx[2]; fb3[tid] = (float)bx[3];
        farea[tid] = (float)ar;
        fscore[tid] = sc;
        svalid[tid] = valid;
    }
    __syncthreads();

    // ---- suppression bitmask: f32 screen (narrow window), cheap f64 recheck
    if (tid < 2 * TOPK) {
        int i = tid >> 1, w = tid & 1;
        unsigned long long m = 0;
        if (svalid[i]) {
            float i0 = fb0[i], i1 = fb1[i], i2 = fb2[i], i3 = fb3[i], ia = farea[i];
            int jbase = w * 64;
            int jend = min(jbase + 64, TOPK);
            int jstart = (jbase > i + 1) ? jbase : (i + 1);
            for (int j = jstart; j < jend; ++j) {
                float tl0 = fmaxf(i0, fb0[j]);
                float tl1 = fmaxf(i1, fb1[j]);
                float br0 = fminf(i2, fb2[j]);
                float br1 = fminf(i3, fb3[j]);
                float wh0 = fmaxf(br0 - tl0, 0.0f);
                float wh1 = fmaxf(br1 - tl1, 0.0f);
                float inter = wh0 * wh1;
                float denom = (ia + farea[j]) - inter;
                bool sup = inter > 0.6004f * denom;
                bool amb = !sup && (inter > 0.5996f * denom) && (inter > 0.0f);
                if (amb) {   // rare; cheap: f64 boxes already in LDS (no exp!)
                    double tl0d = fmax(sb0[i], sb0[j]);
                    double tl1d = fmax(sb1[i], sb1[j]);
                    double br0d = fmin(sb2[i], sb2[j]);
                    double br1d = fmin(sb3[i], sb3[j]);
                    double wh0d = br0d - tl0d; if (wh0d < 0.0) wh0d = 0.0;
                    double wh1d = br1d - tl1d; if (wh1d < 0.0) wh1d = 0.0;
                    double interd = wh0d * wh1d;
                    double denomd = ((sarea[i] + sarea[j]) - interd) + 1e-9;
                    sup = interd > 0.6 * denomd;
                }
                if (sup) m |= 1ull << (j - jbase);
            }
        }
        supmask[i][w] = m;
    }
    __syncthreads();

    // ---- greedy scan on wave 0: masks in registers, shfl broadcast, no LDS chain
    if (tid < 64) {
        unsigned long long m0A = supmask[tid][0], m1A = supmask[tid][1];
        int vA = svalid[tid];
        unsigned long long m0B = 0, m1B = 0; int vB = 0;
        if (tid < TOPK - 64) {
            m0B = supmask[64 + tid][0]; m1B = supmask[64 + tid][1];
            vB = svalid[64 + tid];
        }
        unsigned long long v0b = __ballot(vA != 0);
        unsigned long long v1b = __ballot(vB != 0);
        unsigned long long kp0 = ~0ull, kp1 = ~0ull;
        for (int i = 0; i < TOPK; ++i) {
            bool low = (i < 64);
            int src = low ? i : (i - 64);
            unsigned long long m0 = low ? __shfl(m0A, src) : __shfl(m0B, src);
            unsigned long long m1 = low ? __shfl(m1A, src) : __shfl(m1B, src);
            bool kb = low ? ((kp0 >> i) & 1ull) : ((kp1 >> (i - 64)) & 1ull);
            bool vb = low ? ((v0b >> i) & 1ull) : ((v1b >> (i - 64)) & 1ull);
            if (kb && vb) { kp0 &= ~m0; kp1 &= ~m1; }
        }
        if (tid == 0) { keepw[0] = kp0; keepw[1] = kp1; }
    }
    __syncthreads();

    // ---- write 5 floats per slot
    if (tid < TOPK) {
        bool kb = (tid < 64) ? ((keepw[0] >> tid) & 1ull)
                             : ((keepw[1] >> (tid - 64)) & 1ull);
        bool kp = kb && (svalid[tid] != 0);
        size_t base = ((size_t)task * TOPK + tid) * 5;
        out[base + 0] = kp ? fb0[tid] : 0.0f;
        out[base + 1] = kp ? fb1[tid] : 0.0f;
        out[base + 2] = kp ? fb2[tid] : 0.0f;
        out[base + 3] = kp ? fb3[tid] : 0.0f;
        out[base + 4] = kp ? fscore[tid] : 0.0f;
    }
}

// ---- Standalone fallback (ws too small): validated R13 path ----
__global__ __launch_bounds__(NTHR) void ssd_nms_fallback(
    const float* __restrict__ logits,
    const float* __restrict__ boxreg,
    const float* __restrict__ priors,
    float* __restrict__ out)
{
    const int task = blockIdx.x;
    const int b = task / NCLS;
    const int c = task % NCLS;
    const int tid = threadIdx.x;

    __shared__ unsigned hist[2048];
    __shared__ unsigned wt4[4];
    __shared__ unsigned long long cand[CAND];
    __shared__ unsigned long long ssel[TOPK];
    __shared__ double sb0[TOPK], sb1[TOPK], sb2[TOPK], sb3[TOPK], sarea[TOPK];
    __shared__ float fb0[TOPK], fb1[TOPK], fb2[TOPK], fb3[TOPK];
    __shared__ float farea[TOPK], fscore[TOPK];
    __shared__ int svalid[TOPK];
    __shared__ unsigned long long supmask[TOPK][2];
    __shared__ unsigned long long keepw[2];
    __shared__ int scal[2];

    const float* lg = logits + ((size_t)b * A_N * C_N) + (c + 1);

    for (int k = tid; k < 2048; k += NTHR) hist[k] = 0;
    for (int i = tid; i < CAND; i += NTHR) cand[i] = 0ull;
    if (tid < TOPK) ssel[tid] = 0ull;
    if (tid == 0) { scal[0] = 0; scal[1] = 1; }
    __syncthreads();

    for (int a = tid; a < A_N; a += NTHR) {
        float x = lg[(size_t)a * C_N];
        if ((double)x > THR_LOGIT) atomicAdd(&hist[mapf(x) >> 21], 1u);
    }
    __syncthreads();
    {
        unsigned s = 0;
        #pragma unroll
        for (int k = 0; k < 8; ++k) s += hist[tid * 8 + k];
        unsigned incl = s;
        int lane = tid & 63;
        #pragma unroll
        for (int off = 1; off < 64; off <<= 1) {
            unsigned v = __shfl_down(incl, off);
            if (lane + off < 64) incl += v;
        }
        if (lane == 0) wt4[tid >> 6] = incl;
        __syncthreads();
        unsigned hi = 0;
        #pragma unroll
        for (int w = 0; w < 4; ++w) if (w > (tid >> 6)) hi += wt4[w];
        unsigned excl = hi + (incl - s);
        if (excl < TOPK && excl + s >= TOPK) {
            unsigned running = excl;
            #pragma unroll
            for (int k = 7; k >= 0; --k) {
                running += hist[tid * 8 + k];
                if (running >= TOPK) { scal[1] = (int)(((unsigned)(tid * 8 + k)) << 21); break; }
            }
        }
    }
    __syncthreads();
    const unsigned cutoff = (unsigned)scal[1];

    for (int a = tid; a < A_N; a += NTHR) {
        float x = lg[(size_t)a * C_N];
        if ((double)x > THR_LOGIT) {
            unsigned u = mapf(x);
            if (u >= cutoff) {
                int p = atomicAdd(&scal[0], 1);
                if (p < CAND) cand[p] = ((unsigned long long)u << 32) | (unsigned)(~(unsigned)a);
            }
        }
    }
    __syncthreads();
    const int M = min(scal[0], CAND);
    {
        int Mr = (M + 7) & ~7;
        for (int i = tid; i < Mr; i += NTHR) {
            unsigned long long mykey = cand[i];
            int rank = 0;
            for (int j = 0; j < Mr; ++j) rank += (cand[j] > mykey) ? 1 : 0;
            if (mykey != 0ull && rank < TOPK) ssel[rank] = mykey;
        }
    }
    __syncthreads();
    if (tid < TOPK) {
        unsigned long long key = ssel[tid];
        int valid = (key != 0ull);
        double bx[4] = {0.0, 0.0, 0.0, 0.0}, ar = 0.0;
        float sc = 0.f;
        if (valid) {
            int a = (int)(~(unsigned)key);
            float x = unmapf((unsigned)(key >> 32));
            sc = 1.0f / (1.0f + __expf(-x));
            float4 r4 = *(const float4*)(boxreg + ((size_t)b * A_N + a) * 4);
            float4 p4 = *(const float4*)(priors + (size_t)a * 4);
            dec64(r4, p4, bx, &ar);
        }
        sb0[tid] = bx[0]; sb1[tid] = bx[1]; sb2[tid] = bx[2]; sb3[tid] = bx[3];
        sarea[tid] = ar;
        fb0[tid] = (float)bx[0]; fb1[tid] = (float)bx[1];
        fb2[tid] = (float)bx[2]; fb3[tid] = (float)bx[3];
        farea[tid] = (float)ar; fscore[tid] = sc; svalid[tid] = valid;
    }
    __syncthreads();
    if (tid < 2 * TOPK) {
        int i = tid >> 1, w = tid & 1;
        unsigned long long m = 0;
        if (svalid[i]) {
            float i0=fb0[i], i1=fb1[i], i2=fb2[i], i3=fb3[i], ia=farea[i];
            int jbase = w * 64, jend = min(jbase + 64, TOPK);
            int jstart = (jbase > i + 1) ? jbase : (i + 1);
            for (int j = jstart; j < jend; ++j) {
                float tl0=fmaxf(i0,fb0[j]), tl1=fmaxf(i1,fb1[j]);
                float br0=fminf(i2,fb2[j]), br1=fminf(i3,fb3[j]);
                float wh0=fmaxf(br0-tl0,0.f), wh1=fmaxf(br1-tl1,0.f);
                float inter=wh0*wh1, denom=(ia+farea[j])-inter;
                bool sup = inter > 0.6004f*denom;
                bool amb = !sup && (inter > 0.5996f*denom) && (inter > 0.f);
                if (amb) {
                    double tl0d = fmax(sb0[i], sb0[j]);
                    double tl1d = fmax(sb1[i], sb1[j]);
                    double br0d = fmin(sb2[i], sb2[j]);
                    double br1d = fmin(sb3[i], sb3[j]);
                    double wh0d = br0d - tl0d; if (wh0d < 0.0) wh0d = 0.0;
                    double wh1d = br1d - tl1d; if (wh1d < 0.0) wh1d = 0.0;
                    double interd = wh0d * wh1d;
                    sup = interd > 0.6 * (((sarea[i] + sarea[j]) - interd) + 1e-9);
                }
                if (sup) m |= 1ull << (j - jbase);
            }
        }
        supmask[i][w] = m;
    }
    __syncthreads();
    if (tid == 0) {
        unsigned long long kp0 = ~0ull, kp1 = ~0ull;
        for (int i = 0; i < TOPK; ++i) {
            bool kb = (i < 64) ? ((kp0 >> i) & 1ull) : ((kp1 >> (i - 64)) & 1ull);
            if (kb && svalid[i]) { kp0 &= ~supmask[i][0]; kp1 &= ~supmask[i][1]; }
        }
        keepw[0] = kp0; keepw[1] = kp1;
    }
    __syncthreads();
    if (tid < TOPK) {
        bool kb = (tid < 64) ? ((keepw[0] >> tid) & 1ull)
                             : ((keepw[1] >> (tid - 64)) & 1ull);
        bool kp = kb && (svalid[tid] != 0);
        size_t base = ((size_t)task * TOPK + tid) * 5;
        out[base + 0] = kp ? fb0[tid] : 0.0f;
        out[base + 1] = kp ? fb1[tid] : 0.0f;
        out[base + 2] = kp ? fb2[tid] : 0.0f;
        out[base + 3] = kp ? fb3[tid] : 0.0f;
        out[base + 4] = kp ? fscore[tid] : 0.0f;
    }
}

extern "C" void kernel_launch(void* const* d_in, const int* in_sizes, int n_in,
                              void* d_out, int out_size, void* d_ws, size_t ws_size,
                              hipStream_t stream) {
    const float* logits = (const float*)d_in[0];
    const float* boxreg = (const float*)d_in[1];
    const float* priors = (const float*)d_in[2];
    float* out = (float*)d_out;

    const size_t cand_bytes  = (size_t)NTASK * CAND * sizeof(unsigned long long); // 10.49 MB
    const size_t count_bytes = (size_t)NTASK * CPAD * sizeof(unsigned);           // 160 KB
    if (ws_size >= cand_bytes + count_bytes) {
        unsigned long long* gcand = (unsigned long long*)d_ws;
        unsigned* gcountP = (unsigned*)((char*)d_ws + cand_bytes);
        hipMemsetAsync(gcountP, 0, count_bytes, stream);
        scatter_cand_kernel<<<dim3(B_N * NCH), dim3(NTHR), 0, stream>>>(
            logits, gcand, gcountP);
        ssd_nms_kernel<<<dim3(NTASK), dim3(NTHR), 0, stream>>>(
            logits, gcand, gcountP, boxreg, priors, out);
    } else {
        ssd_nms_fallback<<<dim3(NTASK), dim3(NTHR), 0, stream>>>(
            logits, boxreg, priors, out);
    }
}

// Round 16
// 96.187 us; speedup vs baseline: 1.6148x; 1.0314x over previous
//
#include <hip/hip_runtime.h>
#include <math.h>

#define A_N   8732
#define C_N   81
#define B_N   32
#define NCLS  80
#define NTASK (B_N * NCLS)
#define TOPK  100
#define NTHR  256
#define CAND  512
#define ACH   128                        // anchors per scatter chunk
#define NCH   ((A_N + ACH - 1) / ACH)    // 69
#define LCAP  16                         // LDS list slots per (block, task)
#define CPAD  16                         // gcount padding: 16 u32 = 64 B per task
#define THR_LOGIT (-0.8472978603872034)  // ln(3/7): sigmoid_f64(x)>0.3 <=> x>THR
#define XFIX  2.1f                       // optimistic gather threshold (mu~156, P(<100)~2.5e-6)

// ---- LDS layout for main kernel (byte offsets, disjoint lifetimes overlaid)
#define OFF_SB0    0        // double[100] -> 800   (overlays hist, post-rank)
#define OFF_SB1    800
#define OFF_SB2    1600
#define OFF_SB3    2400
#define OFF_SAREA  3200     // -> 4000
#define OFF_KEEPW  4000     // u64[2] -> 4016
#define OFF_HIST   0        // unsigned[2048] -> 8192 (fallback path only)
#define OFF_CAND   8192     // u64[512] -> 12288 (dead after rank)
#define OFF_FB0    8192     // float[100] (overlays cand, post-rank)
#define OFF_FB1    8592
#define OFF_FB2    8992
#define OFF_FB3    9392
#define OFF_FAREA  9792
#define OFF_FSC    10192
#define OFF_SVAL   10592    // int[100] -> 10992
#define OFF_SSEL   12288    // u64[100] -> 13088
#define OFF_SUP    13088    // u64[100][2] -> 14688
#define OFF_WT4    14688
#define OFF_SCAL   14704    // -> 14712
#define SMEM_SZ    14720

__device__ __forceinline__ unsigned mapf(float x) {
    unsigned b = __float_as_uint(x);
    return b ^ ((b & 0x80000000u) ? 0xFFFFFFFFu : 0x80000000u);
}
__device__ __forceinline__ float unmapf(unsigned u) {
    unsigned b = (u & 0x80000000u) ? (u ^ 0x80000000u) : ~u;
    return __uint_as_float(b);
}

// Exact f64 decode (reference op order) from raw regression/prior values.
__device__ __forceinline__ void dec64(const float4 r4, const float4 p4,
                                      double* bx, double* area) {
    double ty = (double)r4.x / 10.0, tx = (double)r4.y / 10.0;
    double th = (double)r4.z / 5.0,  tw = (double)r4.w / 5.0;
    double cy = ty * (double)p4.z + (double)p4.x;
    double cx = tx * (double)p4.w + (double)p4.y;
    double hh = exp(th) * (double)p4.z;
    double ww = exp(tw) * (double)p4.w;
    bx[0] = cy - hh / 2.0; bx[1] = cx - ww / 2.0;
    bx[2] = cy + hh / 2.0; bx[3] = cx + ww / 2.0;
    double e0 = bx[2] - bx[0]; if (e0 < 0.0) e0 = 0.0;
    double e1 = bx[3] - bx[1]; if (e1 < 0.0) e1 = 0.0;
    *area = e0 * e1;
}

// ---- Kernel S: contiguous slab read + LDS-aggregated candidate scatter ----
// Slab start E0 = 81*(b*8732 + 128*ck) and length NE = 81*an are both == 0 mod 4,
// so float4 tiling is exact: no per-element boundary checks needed.
__global__ __launch_bounds__(NTHR) void scatter_cand_kernel(
    const float* __restrict__ logits,            // (B, A, 81)
    unsigned long long* __restrict__ gcand,      // (NTASK, CAND) full sort keys
    unsigned* __restrict__ gcountP)              // (NTASK * CPAD) padded counters
{
    __shared__ unsigned long long llist[NCLS * LCAP];   // 10 KB
    __shared__ unsigned lcnt[NCLS];
    __shared__ unsigned sbase[NCLS];

    const int b  = blockIdx.x / NCH;
    const int ck = blockIdx.x % NCH;
    const int a0 = ck * ACH;
    const int an = min(ACH, A_N - a0);
    const int tid = threadIdx.x;

    for (int i = tid; i < NCLS; i += NTHR) lcnt[i] = 0;
    __syncthreads();

    const unsigned NE4 = (unsigned)(an * C_N) / 4u;     // exact (NE % 4 == 0)
    const float4* src4 = (const float4*)logits
                       + ((size_t)C_N * ((size_t)b * A_N + a0)) / 4;

    for (unsigned f = tid; f < NE4; f += NTHR) {
        float4 v = src4[f];
        float mx = fmaxf(fmaxf(v.x, v.y), fmaxf(v.z, v.w));
        if (mx < XFIX) continue;                        // ~92% of quads skip
        unsigned e = f * 4u;                            // slab-relative element idx
        float xs[4] = { v.x, v.y, v.z, v.w };
        #pragma unroll
        for (int k = 0; k < 4; ++k) {
            if (xs[k] >= XFIX) {
                unsigned rel = e + (unsigned)k;
                unsigned ar = rel / (unsigned)C_N;      // const-div (magic mul)
                unsigned ch = rel - ar * (unsigned)C_N;
                if (ch > 0) {
                    int t = (int)ch - 1;
                    unsigned a = (unsigned)a0 + ar;
                    unsigned long long key =
                        ((unsigned long long)mapf(xs[k]) << 32) | (unsigned)(~a);
                    unsigned pos = atomicAdd(&lcnt[t], 1u);
                    if (pos < LCAP) {
                        llist[t * LCAP + pos] = key;
                    } else {                             // ~never: direct append
                        int task = b * NCLS + t;
                        unsigned p = atomicAdd(&gcountP[task * CPAD], 1u);
                        if (p < CAND) gcand[(size_t)task * CAND + p] = key;
                    }
                }
            }
        }
    }
    __syncthreads();

    if (tid < NCLS) {
        unsigned n = lcnt[tid]; if (n > LCAP) n = LCAP;
        sbase[tid] = n ? atomicAdd(&gcountP[(b * NCLS + tid) * CPAD], n) : 0u;
        lcnt[tid] = n;
    }
    __syncthreads();

    for (int i = tid; i < NCLS * LCAP; i += NTHR) {
        int t = i >> 4, s = i & (LCAP - 1);
        if ((unsigned)s < lcnt[t]) {
            unsigned dst = sbase[t] + (unsigned)s;
            if (dst < CAND)
                gcand[(size_t)(b * NCLS + t) * CAND + dst] = llist[i];
        }
    }
}

// ---- Kernel M: one task per block; all-pairs rank; shfl greedy scan ----
__global__ __launch_bounds__(NTHR) void ssd_nms_kernel(
    const float* __restrict__ logits,
    const unsigned long long* __restrict__ gcand,
    const unsigned* __restrict__ gcountP,
    const float* __restrict__ boxreg,
    const float* __restrict__ priors,
    float* __restrict__ out)
{
    const int task = blockIdx.x;
    const int b = task / NCLS;
    const int c = task % NCLS;
    const int tid = threadIdx.x;

    __shared__ __align__(16) char smem[SMEM_SZ];
    unsigned* hist = (unsigned*)(smem + OFF_HIST);
    unsigned long long* cand = (unsigned long long*)(smem + OFF_CAND);
    unsigned long long* ssel = (unsigned long long*)(smem + OFF_SSEL);
    unsigned* wt4 = (unsigned*)(smem + OFF_WT4);
    int* scal = (int*)(smem + OFF_SCAL);
    double* sb0 = (double*)(smem + OFF_SB0);
    double* sb1 = (double*)(smem + OFF_SB1);
    double* sb2 = (double*)(smem + OFF_SB2);
    double* sb3 = (double*)(smem + OFF_SB3);
    double* sarea = (double*)(smem + OFF_SAREA);
    float* fb0 = (float*)(smem + OFF_FB0);
    float* fb1 = (float*)(smem + OFF_FB1);
    float* fb2 = (float*)(smem + OFF_FB2);
    float* fb3 = (float*)(smem + OFF_FB3);
    float* farea = (float*)(smem + OFF_FAREA);
    float* fscore = (float*)(smem + OFF_FSC);
    int* svalid = (int*)(smem + OFF_SVAL);
    unsigned long long (*supmask)[2] = (unsigned long long (*)[2])(smem + OFF_SUP);
    unsigned long long* keepw = (unsigned long long*)(smem + OFF_KEEPW);

    const float* lg = logits + ((size_t)b * A_N * C_N) + (c + 1);

    if (tid < TOPK) ssel[tid] = 0ull;
    if (tid == 0) { scal[0] = 0; scal[1] = 1; }

    const int count = (int)gcountP[task * CPAD];
    int M;
    if (count >= TOPK && count <= CAND) {
        // ---- optimistic: keys already assembled by the scatter kernel
        M = count;
        const unsigned long long* lst = gcand + (size_t)task * CAND;
        for (int i = tid; i < M; i += NTHR) cand[i] = lst[i];
    } else {
        // ---- fallback: full strided scan (rare / degenerate data)
        for (int k = tid; k < 2048; k += NTHR) hist[k] = 0;
        __syncthreads();
        for (int a = tid; a < A_N; a += NTHR) {
            float x = lg[(size_t)a * C_N];
            if ((double)x > THR_LOGIT) atomicAdd(&hist[mapf(x) >> 21], 1u);
        }
        __syncthreads();
        {
            unsigned s = 0;
            #pragma unroll
            for (int k = 0; k < 8; ++k) s += hist[tid * 8 + k];
            unsigned incl = s;
            int lane = tid & 63;
            #pragma unroll
            for (int off = 1; off < 64; off <<= 1) {
                unsigned v = __shfl_down(incl, off);
                if (lane + off < 64) incl += v;
            }
            if (lane == 0) wt4[tid >> 6] = incl;
            __syncthreads();
            unsigned hi = 0;
            #pragma unroll
            for (int w = 0; w < 4; ++w) if (w > (tid >> 6)) hi += wt4[w];
            unsigned excl = hi + (incl - s);
            if (excl < TOPK && excl + s >= TOPK) {
                unsigned running = excl;
                #pragma unroll
                for (int k = 7; k >= 0; --k) {
                    running += hist[tid * 8 + k];
                    if (running >= TOPK) { scal[1] = (int)(((unsigned)(tid * 8 + k)) << 21); break; }
                }
            }
        }
        __syncthreads();
        const unsigned cutoff = (unsigned)scal[1];
        for (int a = tid; a < A_N; a += NTHR) {
            float x = lg[(size_t)a * C_N];
            if ((double)x > THR_LOGIT) {
                unsigned u = mapf(x);
                if (u >= cutoff) {
                    int p = atomicAdd(&scal[0], 1);
                    if (p < CAND) cand[p] = ((unsigned long long)u << 32) | (unsigned)(~(unsigned)a);
                }
            }
        }
        __syncthreads();
        M = min(scal[0], CAND);
    }
    {   // zero pad slots for the rank loop
        int Mr = (M + 7) & ~7;
        for (int i = M + tid; i < Mr; i += NTHR) cand[i] = 0ull;
    }
    __syncthreads();

    // ---- exact rank via all-pairs (order-independent, LDS broadcast reads)
    {
        int Mr = (M + 7) & ~7;
        for (int i = tid; i < Mr; i += NTHR) {
            unsigned long long mykey = cand[i];
            int rank = 0;
            #pragma unroll 8
            for (int j = 0; j < Mr; ++j) rank += (cand[j] > mykey) ? 1 : 0;
            if (mykey != 0ull && rank < TOPK) ssel[rank] = mykey;
        }
    }
    __syncthreads();

    // ---- decode top-100: f64 ONCE per box -> LDS; f32 shadows are casts
    if (tid < TOPK) {
        unsigned long long key = ssel[tid];
        int valid = (key != 0ull);
        double bx[4] = {0.0, 0.0, 0.0, 0.0}, ar = 0.0;
        float sc = 0.f;
        if (valid) {
            int a = (int)(~(unsigned)key);
            float x = unmapf((unsigned)(key >> 32));
            sc = 1.0f / (1.0f + __expf(-x));
            float4 r4 = *(const float4*)(boxreg + ((size_t)b * A_N + a) * 4);
            float4 p4 = *(const float4*)(priors + (size_t)a * 4);
            dec64(r4, p4, bx, &ar);
        }
        sb0[tid] = bx[0]; sb1[tid] = bx[1]; sb2[tid] = bx[2]; sb3[tid] = bx[3];
        sarea[tid] = ar;
        fb0[tid] = (float)bx[0]; fb1[tid] = (float)bx[1];
        fb2[tid] = (float)bx[2]; fb3[tid] = (float)bx[3];
        farea[tid] = (float)ar;
        fscore[tid] = sc;
        svalid[tid] = valid;
    }
    __syncthreads();

    // ---- suppression bitmask: f32 screen (narrow window), cheap f64 recheck
    if (tid < 2 * TOPK) {
        int i = tid >> 1, w = tid & 1;
        unsigned long long m = 0;
        if (svalid[i]) {
            float i0 = fb0[i], i1 = fb1[i], i2 = fb2[i], i3 = fb3[i], ia = farea[i];
            int jbase = w * 64;
            int jend = min(jbase + 64, TOPK);
            int jstart = (jbase > i + 1) ? jbase : (i + 1);
            for (int j = jstart; j < jend; ++j) {
                float tl0 = fmaxf(i0, fb0[j]);
                float tl1 = fmaxf(i1, fb1[j]);
                float br0 = fminf(i2, fb2[j]);
                float br1 = fminf(i3, fb3[j]);
                float wh0 = fmaxf(br0 - tl0, 0.0f);
                float wh1 = fmaxf(br1 - tl1, 0.0f);
                float inter = wh0 * wh1;
                float denom = (ia + farea[j]) - inter;
                bool sup = inter > 0.6004f * denom;
                bool amb = !sup && (inter > 0.5996f * denom) && (inter > 0.0f);
                if (amb) {   // rare; cheap: f64 boxes already in LDS (no exp!)
                    double tl0d = fmax(sb0[i], sb0[j]);
                    double tl1d = fmax(sb1[i], sb1[j]);
                    double br0d = fmin(sb2[i], sb2[j]);
                    double br1d = fmin(sb3[i], sb3[j]);
                    double wh0d = br0d - tl0d; if (wh0d < 0.0) wh0d = 0.0;
                    double wh1d = br1d - tl1d; if (wh1d < 0.0) wh1d = 0.0;
                    double interd = wh0d * wh1d;
                    double denomd = ((sarea[i] + sarea[j]) - interd) + 1e-9;
                    sup = interd > 0.6 * denomd;
                }
                if (sup) m |= 1ull << (j - jbase);
            }
        }
        supmask[i][w] = m;
    }
    __syncthreads();

    // ---- greedy scan on wave 0: masks in registers, shfl broadcast chain
    if (tid < 64) {
        unsigned long long m0A = supmask[tid][0], m1A = supmask[tid][1];
        int vA = svalid[tid];
        unsigned long long m0B = 0, m1B = 0; int vB = 0;
        if (tid < TOPK - 64) {
            m0B = supmask[64 + tid][0]; m1B = supmask[64 + tid][1];
            vB = svalid[64 + tid];
        }
        unsigned long long v0b = __ballot(vA != 0);
        unsigned long long v1b = __ballot(vB != 0);
        unsigned long long kp0 = ~0ull, kp1 = ~0ull;
        for (int i = 0; i < TOPK; ++i) {
            bool low = (i < 64);
            int src = low ? i : (i - 64);
            unsigned long long m0 = low ? __shfl(m0A, src) : __shfl(m0B, src);
            unsigned long long m1 = low ? __shfl(m1A, src) : __shfl(m1B, src);
            bool kb = low ? ((kp0 >> i) & 1ull) : ((kp1 >> (i - 64)) & 1ull);
            bool vb = low ? ((v0b >> i) & 1ull) : ((v1b >> (i - 64)) & 1ull);
            if (kb && vb) { kp0 &= ~m0; kp1 &= ~m1; }
        }
        if (tid == 0) { keepw[0] = kp0; keepw[1] = kp1; }
    }
    __syncthreads();

    // ---- write 5 floats per slot
    if (tid < TOPK) {
        bool kb = (tid < 64) ? ((keepw[0] >> tid) & 1ull)
                             : ((keepw[1] >> (tid - 64)) & 1ull);
        bool kp = kb && (svalid[tid] != 0);
        size_t base = ((size_t)task * TOPK + tid) * 5;
        out[base + 0] = kp ? fb0[tid] : 0.0f;
        out[base + 1] = kp ? fb1[tid] : 0.0f;
        out[base + 2] = kp ? fb2[tid] : 0.0f;
        out[base + 3] = kp ? fb3[tid] : 0.0f;
        out[base + 4] = kp ? fscore[tid] : 0.0f;
    }
}

// ---- Standalone fallback (ws too small): validated R13 path ----
__global__ __launch_bounds__(NTHR) void ssd_nms_fallback(
    const float* __restrict__ logits,
    const float* __restrict__ boxreg,
    const float* __restrict__ priors,
    float* __restrict__ out)
{
    const int task = blockIdx.x;
    const int b = task / NCLS;
    const int c = task % NCLS;
    const int tid = threadIdx.x;

    __shared__ unsigned hist[2048];
    __shared__ unsigned wt4[4];
    __shared__ unsigned long long cand[CAND];
    __shared__ unsigned long long ssel[TOPK];
    __shared__ double sb0[TOPK], sb1[TOPK], sb2[TOPK], sb3[TOPK], sarea[TOPK];
    __shared__ float fb0[TOPK], fb1[TOPK], fb2[TOPK], fb3[TOPK];
    __shared__ float farea[TOPK], fscore[TOPK];
    __shared__ int svalid[TOPK];
    __shared__ unsigned long long supmask[TOPK][2];
    __shared__ unsigned long long keepw[2];
    __shared__ int scal[2];

    const float* lg = logits + ((size_t)b * A_N * C_N) + (c + 1);

    for (int k = tid; k < 2048; k += NTHR) hist[k] = 0;
    for (int i = tid; i < CAND; i += NTHR) cand[i] = 0ull;
    if (tid < TOPK) ssel[tid] = 0ull;
    if (tid == 0) { scal[0] = 0; scal[1] = 1; }
    __syncthreads();

    for (int a = tid; a < A_N; a += NTHR) {
        float x = lg[(size_t)a * C_N];
        if ((double)x > THR_LOGIT) atomicAdd(&hist[mapf(x) >> 21], 1u);
    }
    __syncthreads();
    {
        unsigned s = 0;
        #pragma unroll
        for (int k = 0; k < 8; ++k) s += hist[tid * 8 + k];
        unsigned incl = s;
        int lane = tid & 63;
        #pragma unroll
        for (int off = 1; off < 64; off <<= 1) {
            unsigned v = __shfl_down(incl, off);
            if (lane + off < 64) incl += v;
        }
        if (lane == 0) wt4[tid >> 6] = incl;
        __syncthreads();
        unsigned hi = 0;
        #pragma unroll
        for (int w = 0; w < 4; ++w) if (w > (tid >> 6)) hi += wt4[w];
        unsigned excl = hi + (incl - s);
        if (excl < TOPK && excl + s >= TOPK) {
            unsigned running = excl;
            #pragma unroll
            for (int k = 7; k >= 0; --k) {
                running += hist[tid * 8 + k];
                if (running >= TOPK) { scal[1] = (int)(((unsigned)(tid * 8 + k)) << 21); break; }
            }
        }
    }
    __syncthreads();
    const unsigned cutoff = (unsigned)scal[1];

    for (int a = tid; a < A_N; a += NTHR) {
        float x = lg[(size_t)a * C_N];
        if ((double)x > THR_LOGIT) {
            unsigned u = mapf(x);
            if (u >= cutoff) {
                int p = atomicAdd(&scal[0], 1);
                if (p < CAND) cand[p] = ((unsigned long long)u << 32) | (unsigned)(~(unsigned)a);
            }
        }
    }
    __syncthreads();
    const int M = min(scal[0], CAND);
    {
        int Mr = (M + 7) & ~7;
        for (int i = tid; i < Mr; i += NTHR) {
            unsigned long long mykey = cand[i];
            int rank = 0;
            for (int j = 0; j < Mr; ++j) rank += (cand[j] > mykey) ? 1 : 0;
            if (mykey != 0ull && rank < TOPK) ssel[rank] = mykey;
        }
    }
    __syncthreads();
    if (tid < TOPK) {
        unsigned long long key = ssel[tid];
        int valid = (key != 0ull);
        double bx[4] = {0.0, 0.0, 0.0, 0.0}, ar = 0.0;
        float sc = 0.f;
        if (valid) {
            int a = (int)(~(unsigned)key);
            float x = unmapf((unsigned)(key >> 32));
            sc = 1.0f / (1.0f + __expf(-x));
            float4 r4 = *(const float4*)(boxreg + ((size_t)b * A_N + a) * 4);
            float4 p4 = *(const float4*)(priors + (size_t)a * 4);
            dec64(r4, p4, bx, &ar);
        }
        sb0[tid] = bx[0]; sb1[tid] = bx[1]; sb2[tid] = bx[2]; sb3[tid] = bx[3];
        sarea[tid] = ar;
        fb0[tid] = (float)bx[0]; fb1[tid] = (float)bx[1];
        fb2[tid] = (float)bx[2]; fb3[tid] = (float)bx[3];
        farea[tid] = (float)ar; fscore[tid] = sc; svalid[tid] = valid;
    }
    __syncthreads();
    if (tid < 2 * TOPK) {
        int i = tid >> 1, w = tid & 1;
        unsigned long long m = 0;
        if (svalid[i]) {
            float i0=fb0[i], i1=fb1[i], i2=fb2[i], i3=fb3[i], ia=farea[i];
            int jbase = w * 64, jend = min(jbase + 64, TOPK);
            int jstart = (jbase > i + 1) ? jbase : (i + 1);
            for (int j = jstart; j < jend; ++j) {
                float tl0=fmaxf(i0,fb0[j]), tl1=fmaxf(i1,fb1[j]);
                float br0=fminf(i2,fb2[j]), br1=fminf(i3,fb3[j]);
                float wh0=fmaxf(br0-tl0,0.f), wh1=fmaxf(br1-tl1,0.f);
                float inter=wh0*wh1, denom=(ia+farea[j])-inter;
                bool sup = inter > 0.6004f*denom;
                bool amb = !sup && (inter > 0.5996f*denom) && (inter > 0.f);
                if (amb) {
                    double tl0d = fmax(sb0[i], sb0[j]);
                    double tl1d = fmax(sb1[i], sb1[j]);
                    double br0d = fmin(sb2[i], sb2[j]);
                    double br1d = fmin(sb3[i], sb3[j]);
                    double wh0d = br0d - tl0d; if (wh0d < 0.0) wh0d = 0.0;
                    double wh1d = br1d - tl1d; if (wh1d < 0.0) wh1d = 0.0;
                    double interd = wh0d * wh1d;
                    sup = interd > 0.6 * (((sarea[i] + sarea[j]) - interd) + 1e-9);
                }
                if (sup) m |= 1ull << (j - jbase);
            }
        }
        supmask[i][w] = m;
    }
    __syncthreads();
    if (tid == 0) {
        unsigned long long kp0 = ~0ull, kp1 = ~0ull;
        for (int i = 0; i < TOPK; ++i) {
            bool kb = (i < 64) ? ((kp0 >> i) & 1ull) : ((kp1 >> (i - 64)) & 1ull);
            if (kb && svalid[i]) { kp0 &= ~supmask[i][0]; kp1 &= ~supmask[i][1]; }
        }
        keepw[0] = kp0; keepw[1] = kp1;
    }
    __syncthreads();
    if (tid < TOPK) {
        bool kb = (tid < 64) ? ((keepw[0] >> tid) & 1ull)
                             : ((keepw[1] >> (tid - 64)) & 1ull);
        bool kp = kb && (svalid[tid] != 0);
        size_t base = ((size_t)task * TOPK + tid) * 5;
        out[base + 0] = kp ? fb0[tid] : 0.0f;
        out[base + 1] = kp ? fb1[tid] : 0.0f;
        out[base + 2] = kp ? fb2[tid] : 0.0f;
        out[base + 3] = kp ? fb3[tid] : 0.0f;
        out[base + 4] = kp ? fscore[tid] : 0.0f;
    }
}

extern "C" void kernel_launch(void* const* d_in, const int* in_sizes, int n_in,
                              void* d_out, int out_size, void* d_ws, size_t ws_size,
                              hipStream_t stream) {
    const float* logits = (const float*)d_in[0];
    const float* boxreg = (const float*)d_in[1];
    const float* priors = (const float*)d_in[2];
    float* out = (float*)d_out;

    const size_t cand_bytes  = (size_t)NTASK * CAND * sizeof(unsigned long long); // 10.49 MB
    const size_t count_bytes = (size_t)NTASK * CPAD * sizeof(unsigned);           // 160 KB
    if (ws_size >= cand_bytes + count_bytes) {
        unsigned long long* gcand = (unsigned long long*)d_ws;
        unsigned* gcountP = (unsigned*)((char*)d_ws + cand_bytes);
        hipMemsetAsync(gcountP, 0, count_bytes, stream);
        scatter_cand_kernel<<<dim3(B_N * NCH), dim3(NTHR), 0, stream>>>(
            logits, gcand, gcountP);
        ssd_nms_kernel<<<dim3(NTASK), dim3(NTHR), 0, stream>>>(
            logits, gcand, gcountP, boxreg, priors, out);
    } else {
        ssd_nms_fallback<<<dim3(NTASK), dim3(NTHR), 0, stream>>>(
            logits, boxreg, priors, out);
    }
}

// Round 17
// 88.631 us; speedup vs baseline: 1.7524x; 1.0852x over previous
//
#include <hip/hip_runtime.h>
#include <math.h>

#define A_N   8732
#define C_N   81
#define B_N   32
#define NCLS  80
#define NTASK (B_N * NCLS)
#define TOPK  100
#define NTHR  256
#define CAND  512
#define ACH   128                        // anchors per scatter chunk
#define NCH   ((A_N + ACH - 1) / ACH)    // 69
#define LCAP  16                         // LDS list slots per (block, task)
#define CPAD  16                         // gcount padding: 16 u32 = 64 B per task
#define THR_LOGIT (-0.8472978603872034)  // ln(3/7): sigmoid_f64(x)>0.3 <=> x>THR
#define XFIX  2.1f                       // optimistic gather threshold (mu~156)

// ---- LDS layout for main kernel (byte offsets, disjoint lifetimes overlaid)
#define OFF_SB0    0        // double[100] -> 800   (overlays hist, post-rank)
#define OFF_SB1    800
#define OFF_SB2    1600
#define OFF_SB3    2400
#define OFF_SAREA  3200     // -> 4000
#define OFF_KEEPW  4000     // u64[2] -> 4016
#define OFF_HIST   0        // unsigned[2048] -> 8192 (fallback path only)
#define OFF_CAND   8192     // u64[512] -> 12288 (dead after rank)
#define OFF_FB0    8192     // float[100] (overlays cand, post-rank)
#define OFF_FB1    8592
#define OFF_FB2    8992
#define OFF_FB3    9392
#define OFF_FAREA  9792
#define OFF_FSC    10192
#define OFF_SVAL   10592    // int[100] -> 10992
#define OFF_SSEL   12288    // u64[100] -> 13088
#define OFF_SUP    13088    // u64[100][2] -> 14688
#define OFF_WT4    14688
#define OFF_SCAL   14704    // -> 14712
#define SMEM_SZ    14720

__device__ __forceinline__ unsigned mapf(float x) {
    unsigned b = __float_as_uint(x);
    return b ^ ((b & 0x80000000u) ? 0xFFFFFFFFu : 0x80000000u);
}
__device__ __forceinline__ float unmapf(unsigned u) {
    unsigned b = (u & 0x80000000u) ? (u ^ 0x80000000u) : ~u;
    return __uint_as_float(b);
}

// Exact f64 decode (reference op order) from raw regression/prior values.
__device__ __forceinline__ void dec64(const float4 r4, const float4 p4,
                                      double* bx, double* area) {
    double ty = (double)r4.x / 10.0, tx = (double)r4.y / 10.0;
    double th = (double)r4.z / 5.0,  tw = (double)r4.w / 5.0;
    double cy = ty * (double)p4.z + (double)p4.x;
    double cx = tx * (double)p4.w + (double)p4.y;
    double hh = exp(th) * (double)p4.z;
    double ww = exp(tw) * (double)p4.w;
    bx[0] = cy - hh / 2.0; bx[1] = cx - ww / 2.0;
    bx[2] = cy + hh / 2.0; bx[3] = cx + ww / 2.0;
    double e0 = bx[2] - bx[0]; if (e0 < 0.0) e0 = 0.0;
    double e1 = bx[3] - bx[1]; if (e1 < 0.0) e1 = 0.0;
    *area = e0 * e1;
}

// ---- Kernel S: contiguous slab read + LDS-aggregated candidate scatter ----
// Slab start and length are both == 0 mod 4 elements -> exact float4 tiling.
// Loads batched 4-deep (Little's law: 1 outstanding load/thread was latency-bound).
__global__ __launch_bounds__(NTHR) void scatter_cand_kernel(
    const float* __restrict__ logits,            // (B, A, 81)
    unsigned long long* __restrict__ gcand,      // (NTASK, CAND) full sort keys
    unsigned* __restrict__ gcountP)              // (NTASK * CPAD) padded counters
{
    __shared__ unsigned long long llist[NCLS * LCAP];   // 10 KB
    __shared__ unsigned lcnt[NCLS];
    __shared__ unsigned sbase[NCLS];

    const int b  = blockIdx.x / NCH;
    const int ck = blockIdx.x % NCH;
    const int a0 = ck * ACH;
    const int an = min(ACH, A_N - a0);
    const int tid = threadIdx.x;

    for (int i = tid; i < NCLS; i += NTHR) lcnt[i] = 0;
    __syncthreads();

    const unsigned NE4 = (unsigned)(an * C_N) / 4u;     // exact (NE % 4 == 0)
    const float4* src4 = (const float4*)logits
                       + ((size_t)C_N * ((size_t)b * A_N + a0)) / 4;

    auto PROC = [&](float4 v, unsigned f) {
        float mx = fmaxf(fmaxf(v.x, v.y), fmaxf(v.z, v.w));
        if (mx < XFIX) return;                          // ~93% of quads skip
        unsigned e = f * 4u;
        float xs[4] = { v.x, v.y, v.z, v.w };
        #pragma unroll
        for (int k = 0; k < 4; ++k) {
            if (xs[k] >= XFIX) {
                unsigned rel = e + (unsigned)k;
                unsigned ar = rel / (unsigned)C_N;      // const-div (magic mul)
                unsigned ch = rel - ar * (unsigned)C_N;
                if (ch > 0) {
                    int t = (int)ch - 1;
                    unsigned a = (unsigned)a0 + ar;
                    unsigned long long key =
                        ((unsigned long long)mapf(xs[k]) << 32) | (unsigned)(~a);
                    unsigned pos = atomicAdd(&lcnt[t], 1u);
                    if (pos < LCAP) {
                        llist[t * LCAP + pos] = key;
                    } else {                             // ~never: direct append
                        int task = b * NCLS + t;
                        unsigned p = atomicAdd(&gcountP[task * CPAD], 1u);
                        if (p < CAND) gcand[(size_t)task * CAND + p] = key;
                    }
                }
            }
        }
    };

    unsigned f = tid;
    for (; f + 3u * NTHR < NE4; f += 4u * NTHR) {       // 4 loads in flight
        float4 v0 = src4[f];
        float4 v1 = src4[f + NTHR];
        float4 v2 = src4[f + 2u * NTHR];
        float4 v3 = src4[f + 3u * NTHR];
        PROC(v0, f);
        PROC(v1, f + NTHR);
        PROC(v2, f + 2u * NTHR);
        PROC(v3, f + 3u * NTHR);
    }
    for (; f < NE4; f += NTHR) PROC(src4[f], f);
    __syncthreads();

    if (tid < NCLS) {
        unsigned n = lcnt[tid]; if (n > LCAP) n = LCAP;
        sbase[tid] = n ? atomicAdd(&gcountP[(b * NCLS + tid) * CPAD], n) : 0u;
        lcnt[tid] = n;
    }
    __syncthreads();

    for (int i = tid; i < NCLS * LCAP; i += NTHR) {
        int t = i >> 4, s = i & (LCAP - 1);
        if ((unsigned)s < lcnt[t]) {
            unsigned dst = sbase[t] + (unsigned)s;
            if (dst < CAND)
                gcand[(size_t)(b * NCLS + t) * CAND + dst] = llist[i];
        }
    }
}

// ---- Kernel M: one task per block (R13-validated structure) ----
__global__ __launch_bounds__(NTHR) void ssd_nms_kernel(
    const float* __restrict__ logits,
    const unsigned long long* __restrict__ gcand,
    const unsigned* __restrict__ gcountP,
    const float* __restrict__ boxreg,
    const float* __restrict__ priors,
    float* __restrict__ out)
{
    const int task = blockIdx.x;
    const int b = task / NCLS;
    const int c = task % NCLS;
    const int tid = threadIdx.x;

    __shared__ __align__(16) char smem[SMEM_SZ];
    unsigned* hist = (unsigned*)(smem + OFF_HIST);
    unsigned long long* cand = (unsigned long long*)(smem + OFF_CAND);
    unsigned long long* ssel = (unsigned long long*)(smem + OFF_SSEL);
    unsigned* wt4 = (unsigned*)(smem + OFF_WT4);
    int* scal = (int*)(smem + OFF_SCAL);
    double* sb0 = (double*)(smem + OFF_SB0);
    double* sb1 = (double*)(smem + OFF_SB1);
    double* sb2 = (double*)(smem + OFF_SB2);
    double* sb3 = (double*)(smem + OFF_SB3);
    double* sarea = (double*)(smem + OFF_SAREA);
    float* fb0 = (float*)(smem + OFF_FB0);
    float* fb1 = (float*)(smem + OFF_FB1);
    float* fb2 = (float*)(smem + OFF_FB2);
    float* fb3 = (float*)(smem + OFF_FB3);
    float* farea = (float*)(smem + OFF_FAREA);
    float* fscore = (float*)(smem + OFF_FSC);
    int* svalid = (int*)(smem + OFF_SVAL);
    unsigned long long (*supmask)[2] = (unsigned long long (*)[2])(smem + OFF_SUP);
    unsigned long long* keepw = (unsigned long long*)(smem + OFF_KEEPW);

    const float* lg = logits + ((size_t)b * A_N * C_N) + (c + 1);

    if (tid < TOPK) ssel[tid] = 0ull;
    if (tid == 0) { scal[0] = 0; scal[1] = 1; }

    const int count = (int)gcountP[task * CPAD];
    int M;
    if (count >= TOPK && count <= CAND) {
        // optimistic: keys already assembled by the scatter kernel
        M = count;
        const unsigned long long* lst = gcand + (size_t)task * CAND;
        for (int i = tid; i < M; i += NTHR) cand[i] = lst[i];
    } else {
        // fallback: full strided scan (rare / degenerate data)
        for (int k = tid; k < 2048; k += NTHR) hist[k] = 0;
        __syncthreads();
        for (int a = tid; a < A_N; a += NTHR) {
            float x = lg[(size_t)a * C_N];
            if ((double)x > THR_LOGIT) atomicAdd(&hist[mapf(x) >> 21], 1u);
        }
        __syncthreads();
        {
            unsigned s = 0;
            #pragma unroll
            for (int k = 0; k < 8; ++k) s += hist[tid * 8 + k];
            unsigned incl = s;
            int lane = tid & 63;
            #pragma unroll
            for (int off = 1; off < 64; off <<= 1) {
                unsigned v = __shfl_down(incl, off);
                if (lane + off < 64) incl += v;
            }
            if (lane == 0) wt4[tid >> 6] = incl;
            __syncthreads();
            unsigned hi = 0;
            #pragma unroll
            for (int w = 0; w < 4; ++w) if (w > (tid >> 6)) hi += wt4[w];
            unsigned excl = hi + (incl - s);
            if (excl < TOPK && excl + s >= TOPK) {
                unsigned running = excl;
                #pragma unroll
                for (int k = 7; k >= 0; --k) {
                    running += hist[tid * 8 + k];
                    if (running >= TOPK) { scal[1] = (int)(((unsigned)(tid * 8 + k)) << 21); break; }
                }
            }
        }
        __syncthreads();
        const unsigned cutoff = (unsigned)scal[1];
        for (int a = tid; a < A_N; a += NTHR) {
            float x = lg[(size_t)a * C_N];
            if ((double)x > THR_LOGIT) {
                unsigned u = mapf(x);
                if (u >= cutoff) {
                    int p = atomicAdd(&scal[0], 1);
                    if (p < CAND) cand[p] = ((unsigned long long)u << 32) | (unsigned)(~(unsigned)a);
                }
            }
        }
        __syncthreads();
        M = min(scal[0], CAND);
    }
    {
        int Mr = (M + 7) & ~7;
        for (int i = M + tid; i < Mr; i += NTHR) cand[i] = 0ull;
    }
    __syncthreads();

    // ---- exact rank via all-pairs (order-independent, LDS broadcast reads)
    {
        int Mr = (M + 7) & ~7;
        for (int i = tid; i < Mr; i += NTHR) {
            unsigned long long mykey = cand[i];
            int rank = 0;
            #pragma unroll 8
            for (int j = 0; j < Mr; ++j) rank += (cand[j] > mykey) ? 1 : 0;
            if (mykey != 0ull && rank < TOPK) ssel[rank] = mykey;
        }
    }
    __syncthreads();

    // ---- decode top-100: f64 ONCE per box -> LDS; f32 shadows are casts
    if (tid < TOPK) {
        unsigned long long key = ssel[tid];
        int valid = (key != 0ull);
        double bx[4] = {0.0, 0.0, 0.0, 0.0}, ar = 0.0;
        float sc = 0.f;
        if (valid) {
            int a = (int)(~(unsigned)key);
            float x = unmapf((unsigned)(key >> 32));
            sc = 1.0f / (1.0f + __expf(-x));
            float4 r4 = *(const float4*)(boxreg + ((size_t)b * A_N + a) * 4);
            float4 p4 = *(const float4*)(priors + (size_t)a * 4);
            dec64(r4, p4, bx, &ar);
        }
        sb0[tid] = bx[0]; sb1[tid] = bx[1]; sb2[tid] = bx[2]; sb3[tid] = bx[3];
        sarea[tid] = ar;
        fb0[tid] = (float)bx[0]; fb1[tid] = (float)bx[1];
        fb2[tid] = (float)bx[2]; fb3[tid] = (float)bx[3];
        farea[tid] = (float)ar;
        fscore[tid] = sc;
        svalid[tid] = valid;
    }
    __syncthreads();

    // ---- suppression bitmask: f32 screen (narrow window), cheap f64 recheck
    if (tid < 2 * TOPK) {
        int i = tid >> 1, w = tid & 1;
        unsigned long long m = 0;
        if (svalid[i]) {
            float i0 = fb0[i], i1 = fb1[i], i2 = fb2[i], i3 = fb3[i], ia = farea[i];
            int jbase = w * 64;
            int jend = min(jbase + 64, TOPK);
            int jstart = (jbase > i + 1) ? jbase : (i + 1);
            for (int j = jstart; j < jend; ++j) {
                float tl0 = fmaxf(i0, fb0[j]);
                float tl1 = fmaxf(i1, fb1[j]);
                float br0 = fminf(i2, fb2[j]);
                float br1 = fminf(i3, fb3[j]);
                float wh0 = fmaxf(br0 - tl0, 0.0f);
                float wh1 = fmaxf(br1 - tl1, 0.0f);
                float inter = wh0 * wh1;
                float denom = (ia + farea[j]) - inter;
                bool sup = inter > 0.6004f * denom;
                bool amb = !sup && (inter > 0.5996f * denom) && (inter > 0.0f);
                if (amb) {   // rare; cheap: f64 boxes already in LDS (no exp!)
                    double tl0d = fmax(sb0[i], sb0[j]);
                    double tl1d = fmax(sb1[i], sb1[j]);
                    double br0d = fmin(sb2[i], sb2[j]);
                    double br1d = fmin(sb3[i], sb3[j]);
                    double wh0d = br0d - tl0d; if (wh0d < 0.0) wh0d = 0.0;
                    double wh1d = br1d - tl1d; if (wh1d < 0.0) wh1d = 0.0;
                    double interd = wh0d * wh1d;
                    double denomd = ((sarea[i] + sarea[j]) - interd) + 1e-9;
                    sup = interd > 0.6 * denomd;
                }
                if (sup) m |= 1ull << (j - jbase);
            }
        }
        supmask[i][w] = m;
    }
    __syncthreads();

    // ---- serial greedy scan over bitmasks (tid 0; loads pipeline well)
    if (tid == 0) {
        unsigned long long kp0 = ~0ull, kp1 = ~0ull;
        for (int i = 0; i < TOPK; ++i) {
            bool kb = (i < 64) ? ((kp0 >> i) & 1ull) : ((kp1 >> (i - 64)) & 1ull);
            if (kb && svalid[i]) { kp0 &= ~supmask[i][0]; kp1 &= ~supmask[i][1]; }
        }
        keepw[0] = kp0; keepw[1] = kp1;
    }
    __syncthreads();

    // ---- write 5 floats per slot
    if (tid < TOPK) {
        bool kb = (tid < 64) ? ((keepw[0] >> tid) & 1ull)
                             : ((keepw[1] >> (tid - 64)) & 1ull);
        bool kp = kb && (svalid[tid] != 0);
        size_t base = ((size_t)task * TOPK + tid) * 5;
        out[base + 0] = kp ? fb0[tid] : 0.0f;
        out[base + 1] = kp ? fb1[tid] : 0.0f;
        out[base + 2] = kp ? fb2[tid] : 0.0f;
        out[base + 3] = kp ? fb3[tid] : 0.0f;
        out[base + 4] = kp ? fscore[tid] : 0.0f;
    }
}

// ---- Standalone fallback (ws too small): validated R13 path ----
__global__ __launch_bounds__(NTHR) void ssd_nms_fallback(
    const float* __restrict__ logits,
    const float* __restrict__ boxreg,
    const float* __restrict__ priors,
    float* __restrict__ out)
{
    const int task = blockIdx.x;
    const int b = task / NCLS;
    const int c = task % NCLS;
    const int tid = threadIdx.x;

    __shared__ unsigned hist[2048];
    __shared__ unsigned wt4[4];
    __shared__ unsigned long long cand[CAND];
    __shared__ unsigned long long ssel[TOPK];
    __shared__ double sb0[TOPK], sb1[TOPK], sb2[TOPK], sb3[TOPK], sarea[TOPK];
    __shared__ float fb0[TOPK], fb1[TOPK], fb2[TOPK], fb3[TOPK];
    __shared__ float farea[TOPK], fscore[TOPK];
    __shared__ int svalid[TOPK];
    __shared__ unsigned long long supmask[TOPK][2];
    __shared__ unsigned long long keepw[2];
    __shared__ int scal[2];

    const float* lg = logits + ((size_t)b * A_N * C_N) + (c + 1);

    for (int k = tid; k < 2048; k += NTHR) hist[k] = 0;
    for (int i = tid; i < CAND; i += NTHR) cand[i] = 0ull;
    if (tid < TOPK) ssel[tid] = 0ull;
    if (tid == 0) { scal[0] = 0; scal[1] = 1; }
    __syncthreads();

    for (int a = tid; a < A_N; a += NTHR) {
        float x = lg[(size_t)a * C_N];
        if ((double)x > THR_LOGIT) atomicAdd(&hist[mapf(x) >> 21], 1u);
    }
    __syncthreads();
    {
        unsigned s = 0;
        #pragma unroll
        for (int k = 0; k < 8; ++k) s += hist[tid * 8 + k];
        unsigned incl = s;
        int lane = tid & 63;
        #pragma unroll
        for (int off = 1; off < 64; off <<= 1) {
            unsigned v = __shfl_down(incl, off);
            if (lane + off < 64) incl += v;
        }
        if (lane == 0) wt4[tid >> 6] = incl;
        __syncthreads();
        unsigned hi = 0;
        #pragma unroll
        for (int w = 0; w < 4; ++w) if (w > (tid >> 6)) hi += wt4[w];
        unsigned excl = hi + (incl - s);
        if (excl < TOPK && excl + s >= TOPK) {
            unsigned running = excl;
            #pragma unroll
            for (int k = 7; k >= 0; --k) {
                running += hist[tid * 8 + k];
                if (running >= TOPK) { scal[1] = (int)(((unsigned)(tid * 8 + k)) << 21); break; }
            }
        }
    }
    __syncthreads();
    const unsigned cutoff = (unsigned)scal[1];

    for (int a = tid; a < A_N; a += NTHR) {
        float x = lg[(size_t)a * C_N];
        if ((double)x > THR_LOGIT) {
            unsigned u = mapf(x);
            if (u >= cutoff) {
                int p = atomicAdd(&scal[0], 1);
                if (p < CAND) cand[p] = ((unsigned long long)u << 32) | (unsigned)(~(unsigned)a);
            }
        }
    }
    __syncthreads();
    const int M = min(scal[0], CAND);
    {
        int Mr = (M + 7) & ~7;
        for (int i = tid; i < Mr; i += NTHR) {
            unsigned long long mykey = cand[i];
            int rank = 0;
            for (int j = 0; j < Mr; ++j) rank += (cand[j] > mykey) ? 1 : 0;
            if (mykey != 0ull && rank < TOPK) ssel[rank] = mykey;
        }
    }
    __syncthreads();
    if (tid < TOPK) {
        unsigned long long key = ssel[tid];
        int valid = (key != 0ull);
        double bx[4] = {0.0, 0.0, 0.0, 0.0}, ar = 0.0;
        float sc = 0.f;
        if (valid) {
            int a = (int)(~(unsigned)key);
            float x = unmapf((unsigned)(key >> 32));
            sc = 1.0f / (1.0f + __expf(-x));
            float4 r4 = *(const float4*)(boxreg + ((size_t)b * A_N + a) * 4);
            float4 p4 = *(const float4*)(priors + (size_t)a * 4);
            dec64(r4, p4, bx, &ar);
        }
        sb0[tid] = bx[0]; sb1[tid] = bx[1]; sb2[tid] = bx[2]; sb3[tid] = bx[3];
        sarea[tid] = ar;
        fb0[tid] = (float)bx[0]; fb1[tid] = (float)bx[1];
        fb2[tid] = (float)bx[2]; fb3[tid] = (float)bx[3];
        farea[tid] = (float)ar; fscore[tid] = sc; svalid[tid] = valid;
    }
    __syncthreads();
    if (tid < 2 * TOPK) {
        int i = tid >> 1, w = tid & 1;
        unsigned long long m = 0;
        if (svalid[i]) {
            float i0=fb0[i], i1=fb1[i], i2=fb2[i], i3=fb3[i], ia=farea[i];
            int jbase = w * 64, jend = min(jbase + 64, TOPK);
            int jstart = (jbase > i + 1) ? jbase : (i + 1);
            for (int j = jstart; j < jend; ++j) {
                float tl0=fmaxf(i0,fb0[j]), tl1=fmaxf(i1,fb1[j]);
                float br0=fminf(i2,fb2[j]), br1=fminf(i3,fb3[j]);
                float wh0=fmaxf(br0-tl0,0.f), wh1=fmaxf(br1-tl1,0.f);
                float inter=wh0*wh1, denom=(ia+farea[j])-inter;
                bool sup = inter > 0.6004f*denom;
                bool amb = !sup && (inter > 0.5996f*denom) && (inter > 0.f);
                if (amb) {
                    double tl0d = fmax(sb0[i], sb0[j]);
                    double tl1d = fmax(sb1[i], sb1[j]);
                    double br0d = fmin(sb2[i], sb2[j]);
                    double br1d = fmin(sb3[i], sb3[j]);
                    double wh0d = br0d - tl0d; if (wh0d < 0.0) wh0d = 0.0;
                    double wh1d = br1d - tl1d; if (wh1d < 0.0) wh1d = 0.0;
                    double interd = wh0d * wh1d;
                    sup = interd > 0.6 * (((sarea[i] + sarea[j]) - interd) + 1e-9);
                }
                if (sup) m |= 1ull << (j - jbase);
            }
        }
        supmask[i][w] = m;
    }
    __syncthreads();
    if (tid == 0) {
        unsigned long long kp0 = ~0ull, kp1 = ~0ull;
        for (int i = 0; i < TOPK; ++i) {
            bool kb = (i < 64) ? ((kp0 >> i) & 1ull) : ((kp1 >> (i - 64)) & 1ull);
            if (kb && svalid[i]) { kp0 &= ~supmask[i][0]; kp1 &= ~supmask[i][1]; }
        }
        keepw[0] = kp0; keepw[1] = kp1;
    }
    __syncthreads();
    if (tid < TOPK) {
        bool kb = (tid < 64) ? ((keepw[0] >> tid) & 1ull)
                             : ((keepw[1] >> (tid - 64)) & 1ull);
        bool kp = kb && (svalid[tid] != 0);
        size_t base = ((size_t)task * TOPK + tid) * 5;
        out[base + 0] = kp ? fb0[tid] : 0.0f;
        out[base + 1] = kp ? fb1[tid] : 0.0f;
        out[base + 2] = kp ? fb2[tid] : 0.0f;
        out[base + 3] = kp ? fb3[tid] : 0.0f;
        out[base + 4] = kp ? fscore[tid] : 0.0f;
    }
}

extern "C" void kernel_launch(void* const* d_in, const int* in_sizes, int n_in,
                              void* d_out, int out_size, void* d_ws, size_t ws_size,
                              hipStream_t stream) {
    const float* logits = (const float*)d_in[0];
    const float* boxreg = (const float*)d_in[1];
    const float* priors = (const float*)d_in[2];
    float* out = (float*)d_out;

    const size_t cand_bytes  = (size_t)NTASK * CAND * sizeof(unsigned long long); // 10.49 MB
    const size_t count_bytes = (size_t)NTASK * CPAD * sizeof(unsigned);           // 160 KB
    if (ws_size >= cand_bytes + count_bytes) {
        unsigned long long* gcand = (unsigned long long*)d_ws;
        unsigned* gcountP = (unsigned*)((char*)d_ws + cand_bytes);
        hipMemsetAsync(gcountP, 0, count_bytes, stream);
        scatter_cand_kernel<<<dim3(B_N * NCH), dim3(NTHR), 0, stream>>>(
            logits, gcand, gcountP);
        ssd_nms_kernel<<<dim3(NTASK), dim3(NTHR), 0, stream>>>(
            logits, gcand, gcountP, boxreg, priors, out);
    } else {
        ssd_nms_fallback<<<dim3(NTASK), dim3(NTHR), 0, stream>>>(
            logits, boxreg, priors, out);
    }
}

// Round 19
// 87.721 us; speedup vs baseline: 1.7706x; 1.0104x over previous
//
#include <hip/hip_runtime.h>
#include <math.h>

#define A_N   8732
#define C_N   81
#define B_N   32
#define NCLS  80
#define NTASK (B_N * NCLS)
#define TOPK  100
#define NTHR  256
#define CAND  512
#define ACH   128                        // anchors per scatter chunk
#define NCH   ((A_N + ACH - 1) / ACH)    // 69
#define LCAP  16                         // LDS list slots per (block, task)
#define CPAD  16                         // gcount padding: 16 u32 = 64 B per task
#define THR_LOGIT (-0.8472978603872034)  // ln(3/7): sigmoid_f64(x)>0.3 <=> x>THR
#define XFIX  2.1f                       // optimistic gather threshold (mu~156)

// ---- LDS layout for main kernel (byte offsets, disjoint lifetimes overlaid)
#define OFF_SB0    0        // double[100] -> 800   (overlays hist, post-rank)
#define OFF_SB1    800
#define OFF_SB2    1600
#define OFF_SB3    2400
#define OFF_SAREA  3200     // -> 4000
#define OFF_KEEPW  4000     // u64[2] -> 4016
#define OFF_HIST   0        // unsigned[2048] -> 8192 (fallback path only)
#define OFF_CAND   8192     // u64[512] -> 12288 (dead after rank)
#define OFF_FB0    8192     // float[100] (overlays cand, post-rank)
#define OFF_FB1    8592
#define OFF_FB2    8992
#define OFF_FB3    9392
#define OFF_FAREA  9792
#define OFF_FSC    10192
#define OFF_SVAL   10592    // int[100] -> 10992
#define OFF_SSEL   12288    // u64[100] -> 13088
#define OFF_SUP    13088    // u64[100][2] -> 14688
#define OFF_WT4    14688
#define OFF_SCAL   14704    // -> 14712
#define SMEM_SZ    14720

__device__ __forceinline__ unsigned mapf(float x) {
    unsigned b = __float_as_uint(x);
    return b ^ ((b & 0x80000000u) ? 0xFFFFFFFFu : 0x80000000u);
}
__device__ __forceinline__ float unmapf(unsigned u) {
    unsigned b = (u & 0x80000000u) ? (u ^ 0x80000000u) : ~u;
    return __uint_as_float(b);
}

// Exact f64 decode (reference op order) from raw regression/prior values.
__device__ __forceinline__ void dec64(const float4 r4, const float4 p4,
                                      double* bx, double* area) {
    double ty = (double)r4.x / 10.0, tx = (double)r4.y / 10.0;
    double th = (double)r4.z / 5.0,  tw = (double)r4.w / 5.0;
    double cy = ty * (double)p4.z + (double)p4.x;
    double cx = tx * (double)p4.w + (double)p4.y;
    double hh = exp(th) * (double)p4.z;
    double ww = exp(tw) * (double)p4.w;
    bx[0] = cy - hh / 2.0; bx[1] = cx - ww / 2.0;
    bx[2] = cy + hh / 2.0; bx[3] = cx + ww / 2.0;
    double e0 = bx[2] - bx[0]; if (e0 < 0.0) e0 = 0.0;
    double e1 = bx[3] - bx[1]; if (e1 < 0.0) e1 = 0.0;
    *area = e0 * e1;
}

// ---- Kernel S: contiguous slab read + LDS-aggregated candidate scatter ----
// Slab start/length are 0 mod 4 elements -> exact float4 tiling, no bounds checks.
// Loads batched 8-deep (Little's law: more in-flight bytes per thread).
__global__ __launch_bounds__(NTHR) void scatter_cand_kernel(
    const float* __restrict__ logits,            // (B, A, 81)
    unsigned long long* __restrict__ gcand,      // (NTASK, CAND) full sort keys
    unsigned* __restrict__ gcountP)              // (NTASK * CPAD) padded counters
{
    __shared__ unsigned long long llist[NCLS * LCAP];   // 10 KB
    __shared__ unsigned lcnt[NCLS];
    __shared__ unsigned sbase[NCLS];

    const int b  = blockIdx.x / NCH;
    const int ck = blockIdx.x % NCH;
    const int a0 = ck * ACH;
    const int an = min(ACH, A_N - a0);
    const int tid = threadIdx.x;

    for (int i = tid; i < NCLS; i += NTHR) lcnt[i] = 0;
    __syncthreads();

    const unsigned NE4 = (unsigned)(an * C_N) / 4u;     // exact (NE % 4 == 0)
    const float4* src4 = (const float4*)logits
                       + ((size_t)C_N * ((size_t)b * A_N + a0)) / 4;

    auto PROC = [&](float4 v, unsigned f) {
        float mx = fmaxf(fmaxf(v.x, v.y), fmaxf(v.z, v.w));
        if (mx < XFIX) return;                          // ~93% of quads skip
        unsigned e = f * 4u;
        float xs[4] = { v.x, v.y, v.z, v.w };
        #pragma unroll
        for (int k = 0; k < 4; ++k) {
            if (xs[k] >= XFIX) {
                unsigned rel = e + (unsigned)k;
                unsigned ar = rel / (unsigned)C_N;      // const-div (magic mul)
                unsigned ch = rel - ar * (unsigned)C_N;
                if (ch > 0) {
                    int t = (int)ch - 1;
                    unsigned a = (unsigned)a0 + ar;
                    unsigned long long key =
                        ((unsigned long long)mapf(xs[k]) << 32) | (unsigned)(~a);
                    unsigned pos = atomicAdd(&lcnt[t], 1u);
                    if (pos < LCAP) {
                        llist[t * LCAP + pos] = key;
                    } else {                             // ~never: direct append
                        int task = b * NCLS + t;
                        unsigned p = atomicAdd(&gcountP[task * CPAD], 1u);
                        if (p < CAND) gcand[(size_t)task * CAND + p] = key;
                    }
                }
            }
        }
    };

    unsigned f = tid;
    for (; f + 7u * NTHR < NE4; f += 8u * NTHR) {       // 8 loads in flight
        float4 v0 = src4[f];
        float4 v1 = src4[f + NTHR];
        float4 v2 = src4[f + 2u * NTHR];
        float4 v3 = src4[f + 3u * NTHR];
        float4 v4 = src4[f + 4u * NTHR];
        float4 v5 = src4[f + 5u * NTHR];
        float4 v6 = src4[f + 6u * NTHR];
        float4 v7 = src4[f + 7u * NTHR];
        PROC(v0, f);               PROC(v1, f + NTHR);
        PROC(v2, f + 2u * NTHR);   PROC(v3, f + 3u * NTHR);
        PROC(v4, f + 4u * NTHR);   PROC(v5, f + 5u * NTHR);
        PROC(v6, f + 6u * NTHR);   PROC(v7, f + 7u * NTHR);
    }
    for (; f < NE4; f += NTHR) PROC(src4[f], f);
    __syncthreads();

    if (tid < NCLS) {
        unsigned n = lcnt[tid]; if (n > LCAP) n = LCAP;
        sbase[tid] = n ? atomicAdd(&gcountP[(b * NCLS + tid) * CPAD], n) : 0u;
        lcnt[tid] = n;
    }
    __syncthreads();

    for (int i = tid; i < NCLS * LCAP; i += NTHR) {
        int t = i >> 4, s = i & (LCAP - 1);
        if ((unsigned)s < lcnt[t]) {
            unsigned dst = sbase[t] + (unsigned)s;
            if (dst < CAND)
                gcand[(size_t)(b * NCLS + t) * CAND + dst] = llist[i];
        }
    }
}

// ---- Kernel M: one task per block (R13/R17-validated structure) ----
__global__ __launch_bounds__(NTHR) void ssd_nms_kernel(
    const float* __restrict__ logits,
    const unsigned long long* __restrict__ gcand,
    const unsigned* __restrict__ gcountP,
    const float* __restrict__ boxreg,
    const float* __restrict__ priors,
    float* __restrict__ out)
{
    const int task = blockIdx.x;
    const int b = task / NCLS;
    const int c = task % NCLS;
    const int tid = threadIdx.x;

    __shared__ __align__(16) char smem[SMEM_SZ];
    unsigned* hist = (unsigned*)(smem + OFF_HIST);
    unsigned long long* cand = (unsigned long long*)(smem + OFF_CAND);
    unsigned long long* ssel = (unsigned long long*)(smem + OFF_SSEL);
    unsigned* wt4 = (unsigned*)(smem + OFF_WT4);
    int* scal = (int*)(smem + OFF_SCAL);
    double* sb0 = (double*)(smem + OFF_SB0);
    double* sb1 = (double*)(smem + OFF_SB1);
    double* sb2 = (double*)(smem + OFF_SB2);
    double* sb3 = (double*)(smem + OFF_SB3);
    double* sarea = (double*)(smem + OFF_SAREA);
    float* fb0 = (float*)(smem + OFF_FB0);
    float* fb1 = (float*)(smem + OFF_FB1);
    float* fb2 = (float*)(smem + OFF_FB2);
    float* fb3 = (float*)(smem + OFF_FB3);
    float* farea = (float*)(smem + OFF_FAREA);
    float* fscore = (float*)(smem + OFF_FSC);
    int* svalid = (int*)(smem + OFF_SVAL);
    unsigned long long (*supmask)[2] = (unsigned long long (*)[2])(smem + OFF_SUP);
    unsigned long long* keepw = (unsigned long long*)(smem + OFF_KEEPW);

    const float* lg = logits + ((size_t)b * A_N * C_N) + (c + 1);

    if (tid < TOPK) ssel[tid] = 0ull;
    if (tid == 0) { scal[0] = 0; scal[1] = 1; }

    const int count = (int)gcountP[task * CPAD];
    int M;
    if (count >= TOPK && count <= CAND) {
        // optimistic: keys already assembled by the scatter kernel
        M = count;
        const unsigned long long* lst = gcand + (size_t)task * CAND;
        for (int i = tid; i < M; i += NTHR) cand[i] = lst[i];
    } else {
        // fallback: full strided scan (rare / degenerate data)
        for (int k = tid; k < 2048; k += NTHR) hist[k] = 0;
        __syncthreads();
        for (int a = tid; a < A_N; a += NTHR) {
            float x = lg[(size_t)a * C_N];
            if ((double)x > THR_LOGIT) atomicAdd(&hist[mapf(x) >> 21], 1u);
        }
        __syncthreads();
        {
            unsigned s = 0;
            #pragma unroll
            for (int k = 0; k < 8; ++k) s += hist[tid * 8 + k];
            unsigned incl = s;
            int lane = tid & 63;
            #pragma unroll
            for (int off = 1; off < 64; off <<= 1) {
                unsigned v = __shfl_down(incl, off);
                if (lane + off < 64) incl += v;
            }
            if (lane == 0) wt4[tid >> 6] = incl;
            __syncthreads();
            unsigned hi = 0;
            #pragma unroll
            for (int w = 0; w < 4; ++w) if (w > (tid >> 6)) hi += wt4[w];
            unsigned excl = hi + (incl - s);
            if (excl < TOPK && excl + s >= TOPK) {
                unsigned running = excl;
                #pragma unroll
                for (int k = 7; k >= 0; --k) {
                    running += hist[tid * 8 + k];
                    if (running >= TOPK) { scal[1] = (int)(((unsigned)(tid * 8 + k)) << 21); break; }
                }
            }
        }
        __syncthreads();
        const unsigned cutoff = (unsigned)scal[1];
        for (int a = tid; a < A_N; a += NTHR) {
            float x = lg[(size_t)a * C_N];
            if ((double)x > THR_LOGIT) {
                unsigned u = mapf(x);
                if (u >= cutoff) {
                    int p = atomicAdd(&scal[0], 1);
                    if (p < CAND) cand[p] = ((unsigned long long)u << 32) | (unsigned)(~(unsigned)a);
                }
            }
        }
        __syncthreads();
        M = min(scal[0], CAND);
    }
    {
        int Mr = (M + 7) & ~7;
        for (int i = M + tid; i < Mr; i += NTHR) cand[i] = 0ull;
    }
    __syncthreads();

    // ---- exact rank via all-pairs (order-independent, LDS broadcast reads)
    {
        int Mr = (M + 7) & ~7;
        for (int i = tid; i < Mr; i += NTHR) {
            unsigned long long mykey = cand[i];
            int rank = 0;
            #pragma unroll 8
            for (int j = 0; j < Mr; ++j) rank += (cand[j] > mykey) ? 1 : 0;
            if (mykey != 0ull && rank < TOPK) ssel[rank] = mykey;
        }
    }
    __syncthreads();

    // ---- decode top-100: f64 ONCE per box -> LDS; f32 shadows are casts
    if (tid < TOPK) {
        unsigned long long key = ssel[tid];
        int valid = (key != 0ull);
        double bx[4] = {0.0, 0.0, 0.0, 0.0}, ar = 0.0;
        float sc = 0.f;
        if (valid) {
            int a = (int)(~(unsigned)key);
            float x = unmapf((unsigned)(key >> 32));
            sc = 1.0f / (1.0f + __expf(-x));
            float4 r4 = *(const float4*)(boxreg + ((size_t)b * A_N + a) * 4);
            float4 p4 = *(const float4*)(priors + (size_t)a * 4);
            dec64(r4, p4, bx, &ar);
        }
        sb0[tid] = bx[0]; sb1[tid] = bx[1]; sb2[tid] = bx[2]; sb3[tid] = bx[3];
        sarea[tid] = ar;
        fb0[tid] = (float)bx[0]; fb1[tid] = (float)bx[1];
        fb2[tid] = (float)bx[2]; fb3[tid] = (float)bx[3];
        farea[tid] = (float)ar;
        fscore[tid] = sc;
        svalid[tid] = valid;
    }
    __syncthreads();

    // ---- suppression bitmask: f32 screen (narrow window), cheap f64 recheck
    if (tid < 2 * TOPK) {
        int i = tid >> 1, w = tid & 1;
        unsigned long long m = 0;
        if (svalid[i]) {
            float i0 = fb0[i], i1 = fb1[i], i2 = fb2[i], i3 = fb3[i], ia = farea[i];
            int jbase = w * 64;
            int jend = min(jbase + 64, TOPK);
            int jstart = (jbase > i + 1) ? jbase : (i + 1);
            for (int j = jstart; j < jend; ++j) {
                float tl0 = fmaxf(i0, fb0[j]);
                float tl1 = fmaxf(i1, fb1[j]);
                float br0 = fminf(i2, fb2[j]);
                float br1 = fminf(i3, fb3[j]);
                float wh0 = fmaxf(br0 - tl0, 0.0f);
                float wh1 = fmaxf(br1 - tl1, 0.0f);
                float inter = wh0 * wh1;
                float denom = (ia + farea[j]) - inter;
                bool sup = inter > 0.6004f * denom;
                bool amb = !sup && (inter > 0.5996f * denom) && (inter > 0.0f);
                if (amb) {   // rare; cheap: f64 boxes already in LDS (no exp!)
                    double tl0d = fmax(sb0[i], sb0[j]);
                    double tl1d = fmax(sb1[i], sb1[j]);
                    double br0d = fmin(sb2[i], sb2[j]);
                    double br1d = fmin(sb3[i], sb3[j]);
                    double wh0d = br0d - tl0d; if (wh0d < 0.0) wh0d = 0.0;
                    double wh1d = br1d - tl1d; if (wh1d < 0.0) wh1d = 0.0;
                    double interd = wh0d * wh1d;
                    double denomd = ((sarea[i] + sarea[j]) - interd) + 1e-9;
                    sup = interd > 0.6 * denomd;
                }
                if (sup) m |= 1ull << (j - jbase);
            }
        }
        supmask[i][w] = m;
    }
    __syncthreads();

    // ---- serial greedy scan over bitmasks (tid 0; loads pipeline well)
    if (tid == 0) {
        unsigned long long kp0 = ~0ull, kp1 = ~0ull;
        for (int i = 0; i < TOPK; ++i) {
            bool kb = (i < 64) ? ((kp0 >> i) & 1ull) : ((kp1 >> (i - 64)) & 1ull);
            if (kb && svalid[i]) { kp0 &= ~supmask[i][0]; kp1 &= ~supmask[i][1]; }
        }
        keepw[0] = kp0; keepw[1] = kp1;
    }
    __syncthreads();

    // ---- write 5 floats per slot
    if (tid < TOPK) {
        bool kb = (tid < 64) ? ((keepw[0] >> tid) & 1ull)
                             : ((keepw[1] >> (tid - 64)) & 1ull);
        bool kp = kb && (svalid[tid] != 0);
        size_t base = ((size_t)task * TOPK + tid) * 5;
        out[base + 0] = kp ? fb0[tid] : 0.0f;
        out[base + 1] = kp ? fb1[tid] : 0.0f;
        out[base + 2] = kp ? fb2[tid] : 0.0f;
        out[base + 3] = kp ? fb3[tid] : 0.0f;
        out[base + 4] = kp ? fscore[tid] : 0.0f;
    }
}

// ---- Standalone fallback (ws too small): validated R13 path ----
__global__ __launch_bounds__(NTHR) void ssd_nms_fallback(
    const float* __restrict__ logits,
    const float* __restrict__ boxreg,
    const float* __restrict__ priors,
    float* __restrict__ out)
{
    const int task = blockIdx.x;
    const int b = task / NCLS;
    const int c = task % NCLS;
    const int tid = threadIdx.x;

    __shared__ unsigned hist[2048];
    __shared__ unsigned wt4[4];
    __shared__ unsigned long long cand[CAND];
    __shared__ unsigned long long ssel[TOPK];
    __shared__ double sb0[TOPK], sb1[TOPK], sb2[TOPK], sb3[TOPK], sarea[TOPK];
    __shared__ float fb0[TOPK], fb1[TOPK], fb2[TOPK], fb3[TOPK];
    __shared__ float farea[TOPK], fscore[TOPK];
    __shared__ int svalid[TOPK];
    __shared__ unsigned long long supmask[TOPK][2];
    __shared__ unsigned long long keepw[2];
    __shared__ int scal[2];

    const float* lg = logits + ((size_t)b * A_N * C_N) + (c + 1);

    for (int k = tid; k < 2048; k += NTHR) hist[k] = 0;
    for (int i = tid; i < CAND; i += NTHR) cand[i] = 0ull;
    if (tid < TOPK) ssel[tid] = 0ull;
    if (tid == 0) { scal[0] = 0; scal[1] = 1; }
    __syncthreads();

    for (int a = tid; a < A_N; a += NTHR) {
        float x = lg[(size_t)a * C_N];
        if ((double)x > THR_LOGIT) atomicAdd(&hist[mapf(x) >> 21], 1u);
    }
    __syncthreads();
    {
        unsigned s = 0;
        #pragma unroll
        for (int k = 0; k < 8; ++k) s += hist[tid * 8 + k];
        unsigned incl = s;
        int lane = tid & 63;
        #pragma unroll
        for (int off = 1; off < 64; off <<= 1) {
            unsigned v = __shfl_down(incl, off);
            if (lane + off < 64) incl += v;
        }
        if (lane == 0) wt4[tid >> 6] = incl;
        __syncthreads();
        unsigned hi = 0;
        #pragma unroll
        for (int w = 0; w < 4; ++w) if (w > (tid >> 6)) hi += wt4[w];
        unsigned excl = hi + (incl - s);
        if (excl < TOPK && excl + s >= TOPK) {
            unsigned running = excl;
            #pragma unroll
            for (int k = 7; k >= 0; --k) {
                running += hist[tid * 8 + k];
                if (running >= TOPK) { scal[1] = (int)(((unsigned)(tid * 8 + k)) << 21); break; }
            }
        }
    }
    __syncthreads();
    const unsigned cutoff = (unsigned)scal[1];

    for (int a = tid; a < A_N; a += NTHR) {
        float x = lg[(size_t)a * C_N];
        if ((double)x > THR_LOGIT) {
            unsigned u = mapf(x);
            if (u >= cutoff) {
                int p = atomicAdd(&scal[0], 1);
                if (p < CAND) cand[p] = ((unsigned long long)u << 32) | (unsigned)(~(unsigned)a);
            }
        }
    }
    __syncthreads();
    const int M = min(scal[0], CAND);
    {
        int Mr = (M + 7) & ~7;
        for (int i = tid; i < Mr; i += NTHR) {
            unsigned long long mykey = cand[i];
            int rank = 0;
            for (int j = 0; j < Mr; ++j) rank += (cand[j] > mykey) ? 1 : 0;
            if (mykey != 0ull && rank < TOPK) ssel[rank] = mykey;
        }
    }
    __syncthreads();
    if (tid < TOPK) {
        unsigned long long key = ssel[tid];
        int valid = (key != 0ull);
        double bx[4] = {0.0, 0.0, 0.0, 0.0}, ar = 0.0;
        float sc = 0.f;
        if (valid) {
            int a = (int)(~(unsigned)key);
            float x = unmapf((unsigned)(key >> 32));
            sc = 1.0f / (1.0f + __expf(-x));
            float4 r4 = *(const float4*)(boxreg + ((size_t)b * A_N + a) * 4);
            float4 p4 = *(const float4*)(priors + (size_t)a * 4);
            dec64(r4, p4, bx, &ar);
        }
        sb0[tid] = bx[0]; sb1[tid] = bx[1]; sb2[tid] = bx[2]; sb3[tid] = bx[3];
        sarea[tid] = ar;
        fb0[tid] = (float)bx[0]; fb1[tid] = (float)bx[1];
        fb2[tid] = (float)bx[2]; fb3[tid] = (float)bx[3];
        farea[tid] = (float)ar; fscore[tid] = sc; svalid[tid] = valid;
    }
    __syncthreads();
    if (tid < 2 * TOPK) {
        int i = tid >> 1, w = tid & 1;
        unsigned long long m = 0;
        if (svalid[i]) {
            float i0=fb0[i], i1=fb1[i], i2=fb2[i], i3=fb3[i], ia=farea[i];
            int jbase = w * 64, jend = min(jbase + 64, TOPK);
            int jstart = (jbase > i + 1) ? jbase : (i + 1);
            for (int j = jstart; j < jend; ++j) {
                float tl0=fmaxf(i0,fb0[j]), tl1=fmaxf(i1,fb1[j]);
                float br0=fminf(i2,fb2[j]), br1=fminf(i3,fb3[j]);
                float wh0=fmaxf(br0-tl0,0.f), wh1=fmaxf(br1-tl1,0.f);
                float inter=wh0*wh1, denom=(ia+farea[j])-inter;
                bool sup = inter > 0.6004f*denom;
                bool amb = !sup && (inter > 0.5996f*denom) && (inter > 0.f);
                if (amb) {
                    double tl0d = fmax(sb0[i], sb0[j]);
                    double tl1d = fmax(sb1[i], sb1[j]);
                    double br0d = fmin(sb2[i], sb2[j]);
                    double br1d = fmin(sb3[i], sb3[j]);
                    double wh0d = br0d - tl0d; if (wh0d < 0.0) wh0d = 0.0;
                    double wh1d = br1d - tl1d; if (wh1d < 0.0) wh1d = 0.0;
                    double interd = wh0d * wh1d;
                    sup = interd > 0.6 * (((sarea[i] + sarea[j]) - interd) + 1e-9);
                }
                if (sup) m |= 1ull << (j - jbase);
            }
        }
        supmask[i][w] = m;
    }
    __syncthreads();
    if (tid == 0) {
        unsigned long long kp0 = ~0ull, kp1 = ~0ull;
        for (int i = 0; i < TOPK; ++i) {
            bool kb = (i < 64) ? ((kp0 >> i) & 1ull) : ((kp1 >> (i - 64)) & 1ull);
            if (kb && svalid[i]) { kp0 &= ~supmask[i][0]; kp1 &= ~supmask[i][1]; }
        }
        keepw[0] = kp0; keepw[1] = kp1;
    }
    __syncthreads();
    if (tid < TOPK) {
        bool kb = (tid < 64) ? ((keepw[0] >> tid) & 1ull)
                             : ((keepw[1] >> (tid - 64)) & 1ull);
        bool kp = kb && (svalid[tid] != 0);
        size_t base = ((size_t)task * TOPK + tid) * 5;
        out[base + 0] = kp ? fb0[tid] : 0.0f;
        out[base + 1] = kp ? fb1[tid] : 0.0f;
        out[base + 2] = kp ? fb2[tid] : 0.0f;
        out[base + 3] = kp ? fb3[tid] : 0.0f;
        out[base + 4] = kp ? fscore[tid] : 0.0f;
    }
}

extern "C" void kernel_launch(void* const* d_in, const int* in_sizes, int n_in,
                              void* d_out, int out_size, void* d_ws, size_t ws_size,
                              hipStream_t stream) {
    const float* logits = (const float*)d_in[0];
    const float* boxreg = (const float*)d_in[1];
    const float* priors = (const float*)d_in[2];
    float* out = (float*)d_out;

    const size_t cand_bytes  = (size_t)NTASK * CAND * sizeof(unsigned long long); // 10.49 MB
    const size_t count_bytes = (size_t)NTASK * CPAD * sizeof(unsigned);           // 160 KB
    if (ws_size >= cand_bytes + count_bytes) {
        unsigned long long* gcand = (unsigned long long*)d_ws;
        unsigned* gcountP = (unsigned*)((char*)d_ws + cand_bytes);
        hipMemsetAsync(gcountP, 0, count_bytes, stream);
        scatter_cand_kernel<<<dim3(B_N * NCH), dim3(NTHR), 0, stream>>>(
            logits, gcand, gcountP);
        ssd_nms_kernel<<<dim3(NTASK), dim3(NTHR), 0, stream>>>(
            logits, gcand, gcountP, boxreg, priors, out);
    } else {
        ssd_nms_fallback<<<dim3(NTASK), dim3(NTHR), 0, stream>>>(
            logits, boxreg, priors, out);
    }
}

// Round 20
// 82.042 us; speedup vs baseline: 1.8932x; 1.0692x over previous
//
#include <hip/hip_runtime.h>
#include <math.h>

#define A_N   8732
#define C_N   81
#define B_N   32
#define NCLS  80
#define NTASK (B_N * NCLS)
#define TOPK  100
#define NTHR  256            // scatter / standalone-fallback block size
#define NTHM  128            // main kernel block size: 10 blocks/CU, all-resident
#define CAND  512
#define ACH   128                        // anchors per scatter chunk
#define NCH   ((A_N + ACH - 1) / ACH)    // 69
#define LCAP  16                         // LDS list slots per (block, task)
#define CPAD  16                         // gcount padding: 16 u32 = 64 B per task
#define THR_LOGIT (-0.8472978603872034)  // ln(3/7): sigmoid_f64(x)>0.3 <=> x>THR
#define XFIX  2.1f                       // optimistic gather threshold (mu~156)

// ---- LDS layout for main kernel (byte offsets, disjoint lifetimes overlaid)
#define OFF_SB0    0        // double[100] -> 800   (overlays hist, post-rank)
#define OFF_SB1    800
#define OFF_SB2    1600
#define OFF_SB3    2400
#define OFF_SAREA  3200     // -> 4000
#define OFF_KEEPW  4000     // u64[2] -> 4016
#define OFF_HIST   0        // unsigned[2048] -> 8192 (fallback path only)
#define OFF_CAND   8192     // u64[512] -> 12288 (dead after rank)
#define OFF_FB0    8192     // float[100] (overlays cand, post-rank)
#define OFF_FB1    8592
#define OFF_FB2    8992
#define OFF_FB3    9392
#define OFF_FAREA  9792
#define OFF_FSC    10192
#define OFF_SVAL   10592    // int[100] -> 10992
#define OFF_SSEL   12288    // u64[100] -> 13088
#define OFF_SUP    13088    // u64[100][2] -> 14688
#define OFF_WT4    14688
#define OFF_SCAL   14704    // -> 14712
#define SMEM_SZ    14720

__device__ __forceinline__ unsigned mapf(float x) {
    unsigned b = __float_as_uint(x);
    return b ^ ((b & 0x80000000u) ? 0xFFFFFFFFu : 0x80000000u);
}
__device__ __forceinline__ float unmapf(unsigned u) {
    unsigned b = (u & 0x80000000u) ? (u ^ 0x80000000u) : ~u;
    return __uint_as_float(b);
}

// Exact f64 decode (reference op order) from raw regression/prior values.
__device__ __forceinline__ void dec64(const float4 r4, const float4 p4,
                                      double* bx, double* area) {
    double ty = (double)r4.x / 10.0, tx = (double)r4.y / 10.0;
    double th = (double)r4.z / 5.0,  tw = (double)r4.w / 5.0;
    double cy = ty * (double)p4.z + (double)p4.x;
    double cx = tx * (double)p4.w + (double)p4.y;
    double hh = exp(th) * (double)p4.z;
    double ww = exp(tw) * (double)p4.w;
    bx[0] = cy - hh / 2.0; bx[1] = cx - ww / 2.0;
    bx[2] = cy + hh / 2.0; bx[3] = cx + ww / 2.0;
    double e0 = bx[2] - bx[0]; if (e0 < 0.0) e0 = 0.0;
    double e1 = bx[3] - bx[1]; if (e1 < 0.0) e1 = 0.0;
    *area = e0 * e1;
}

// ---- Kernel S: contiguous slab read + LDS-aggregated candidate scatter ----
__global__ __launch_bounds__(NTHR) void scatter_cand_kernel(
    const float* __restrict__ logits,            // (B, A, 81)
    unsigned long long* __restrict__ gcand,      // (NTASK, CAND) full sort keys
    unsigned* __restrict__ gcountP)              // (NTASK * CPAD) padded counters
{
    __shared__ unsigned long long llist[NCLS * LCAP];   // 10 KB
    __shared__ unsigned lcnt[NCLS];
    __shared__ unsigned sbase[NCLS];

    const int b  = blockIdx.x / NCH;
    const int ck = blockIdx.x % NCH;
    const int a0 = ck * ACH;
    const int an = min(ACH, A_N - a0);
    const int tid = threadIdx.x;

    for (int i = tid; i < NCLS; i += NTHR) lcnt[i] = 0;
    __syncthreads();

    const unsigned NE4 = (unsigned)(an * C_N) / 4u;     // exact (NE % 4 == 0)
    const float4* src4 = (const float4*)logits
                       + ((size_t)C_N * ((size_t)b * A_N + a0)) / 4;

    auto PROC = [&](float4 v, unsigned f) {
        float mx = fmaxf(fmaxf(v.x, v.y), fmaxf(v.z, v.w));
        if (mx < XFIX) return;                          // ~93% of quads skip
        unsigned e = f * 4u;
        float xs[4] = { v.x, v.y, v.z, v.w };
        #pragma unroll
        for (int k = 0; k < 4; ++k) {
            if (xs[k] >= XFIX) {
                unsigned rel = e + (unsigned)k;
                unsigned ar = rel / (unsigned)C_N;      // const-div (magic mul)
                unsigned ch = rel - ar * (unsigned)C_N;
                if (ch > 0) {
                    int t = (int)ch - 1;
                    unsigned a = (unsigned)a0 + ar;
                    unsigned long long key =
                        ((unsigned long long)mapf(xs[k]) << 32) | (unsigned)(~a);
                    unsigned pos = atomicAdd(&lcnt[t], 1u);
                    if (pos < LCAP) {
                        llist[t * LCAP + pos] = key;
                    } else {                             // ~never: direct append
                        int task = b * NCLS + t;
                        unsigned p = atomicAdd(&gcountP[task * CPAD], 1u);
                        if (p < CAND) gcand[(size_t)task * CAND + p] = key;
                    }
                }
            }
        }
    };

    unsigned f = tid;
    for (; f + 7u * NTHR < NE4; f += 8u * NTHR) {       // 8 loads in flight
        float4 v0 = src4[f];
        float4 v1 = src4[f + NTHR];
        float4 v2 = src4[f + 2u * NTHR];
        float4 v3 = src4[f + 3u * NTHR];
        float4 v4 = src4[f + 4u * NTHR];
        float4 v5 = src4[f + 5u * NTHR];
        float4 v6 = src4[f + 6u * NTHR];
        float4 v7 = src4[f + 7u * NTHR];
        PROC(v0, f);               PROC(v1, f + NTHR);
        PROC(v2, f + 2u * NTHR);   PROC(v3, f + 3u * NTHR);
        PROC(v4, f + 4u * NTHR);   PROC(v5, f + 5u * NTHR);
        PROC(v6, f + 6u * NTHR);   PROC(v7, f + 7u * NTHR);
    }
    for (; f < NE4; f += NTHR) PROC(src4[f], f);
    __syncthreads();

    if (tid < NCLS) {
        unsigned n = lcnt[tid]; if (n > LCAP) n = LCAP;
        sbase[tid] = n ? atomicAdd(&gcountP[(b * NCLS + tid) * CPAD], n) : 0u;
        lcnt[tid] = n;
    }
    __syncthreads();

    for (int i = tid; i < NCLS * LCAP; i += NTHR) {
        int t = i >> 4, s = i & (LCAP - 1);
        if ((unsigned)s < lcnt[t]) {
            unsigned dst = sbase[t] + (unsigned)s;
            if (dst < CAND)
                gcand[(size_t)(b * NCLS + t) * CAND + dst] = llist[i];
        }
    }
}

// ---- Kernel M: one task per 128-thread block; 10 blocks/CU all-resident ----
__global__ __launch_bounds__(NTHM) void ssd_nms_kernel(
    const float* __restrict__ logits,
    const unsigned long long* __restrict__ gcand,
    const unsigned* __restrict__ gcountP,
    const float* __restrict__ boxreg,
    const float* __restrict__ priors,
    float* __restrict__ out)
{
    const int task = blockIdx.x;
    const int b = task / NCLS;
    const int c = task % NCLS;
    const int tid = threadIdx.x;

    __shared__ __align__(16) char smem[SMEM_SZ];
    unsigned* hist = (unsigned*)(smem + OFF_HIST);
    unsigned long long* cand = (unsigned long long*)(smem + OFF_CAND);
    unsigned long long* ssel = (unsigned long long*)(smem + OFF_SSEL);
    unsigned* wt4 = (unsigned*)(smem + OFF_WT4);
    int* scal = (int*)(smem + OFF_SCAL);
    double* sb0 = (double*)(smem + OFF_SB0);
    double* sb1 = (double*)(smem + OFF_SB1);
    double* sb2 = (double*)(smem + OFF_SB2);
    double* sb3 = (double*)(smem + OFF_SB3);
    double* sarea = (double*)(smem + OFF_SAREA);
    float* fb0 = (float*)(smem + OFF_FB0);
    float* fb1 = (float*)(smem + OFF_FB1);
    float* fb2 = (float*)(smem + OFF_FB2);
    float* fb3 = (float*)(smem + OFF_FB3);
    float* farea = (float*)(smem + OFF_FAREA);
    float* fscore = (float*)(smem + OFF_FSC);
    int* svalid = (int*)(smem + OFF_SVAL);
    unsigned long long (*supmask)[2] = (unsigned long long (*)[2])(smem + OFF_SUP);
    unsigned long long* keepw = (unsigned long long*)(smem + OFF_KEEPW);

    const float* lg = logits + ((size_t)b * A_N * C_N) + (c + 1);

    if (tid < TOPK) ssel[tid] = 0ull;
    if (tid == 0) { scal[0] = 0; scal[1] = 1; }

    const int count = (int)gcountP[task * CPAD];
    int M;
    if (count >= TOPK && count <= CAND) {
        // optimistic: keys already assembled by the scatter kernel
        M = count;
        const unsigned long long* lst = gcand + (size_t)task * CAND;
        for (int i = tid; i < M; i += NTHM) cand[i] = lst[i];
    } else {
        // fallback: full strided scan (rare / degenerate data) — 128-thread form
        for (int k = tid; k < 2048; k += NTHM) hist[k] = 0;
        __syncthreads();
        for (int a = tid; a < A_N; a += NTHM) {
            float x = lg[(size_t)a * C_N];
            if ((double)x > THR_LOGIT) atomicAdd(&hist[mapf(x) >> 21], 1u);
        }
        __syncthreads();
        {
            unsigned s = 0;
            #pragma unroll
            for (int k = 0; k < 16; ++k) s += hist[tid * 16 + k];
            unsigned incl = s;
            int lane = tid & 63;
            #pragma unroll
            for (int off = 1; off < 64; off <<= 1) {
                unsigned v = __shfl_down(incl, off);
                if (lane + off < 64) incl += v;
            }
            if (lane == 0) wt4[tid >> 6] = incl;     // waves 0,1
            __syncthreads();
            unsigned hi = (tid < 64) ? wt4[1] : 0u;  // sum of waves above mine
            unsigned excl = hi + (incl - s);
            if (excl < TOPK && excl + s >= TOPK) {
                unsigned running = excl;
                #pragma unroll
                for (int k = 15; k >= 0; --k) {
                    running += hist[tid * 16 + k];
                    if (running >= TOPK) { scal[1] = (int)(((unsigned)(tid * 16 + k)) << 21); break; }
                }
            }
        }
        __syncthreads();
        const unsigned cutoff = (unsigned)scal[1];
        for (int a = tid; a < A_N; a += NTHM) {
            float x = lg[(size_t)a * C_N];
            if ((double)x > THR_LOGIT) {
                unsigned u = mapf(x);
                if (u >= cutoff) {
                    int p = atomicAdd(&scal[0], 1);
                    if (p < CAND) cand[p] = ((unsigned long long)u << 32) | (unsigned)(~(unsigned)a);
                }
            }
        }
        __syncthreads();
        M = min(scal[0], CAND);
    }
    {
        int Mr = (M + 7) & ~7;
        for (int i = M + tid; i < Mr; i += NTHM) cand[i] = 0ull;
    }
    __syncthreads();

    // ---- exact rank via all-pairs (order-independent, LDS broadcast reads)
    {
        int Mr = (M + 7) & ~7;
        for (int i = tid; i < Mr; i += NTHM) {
            unsigned long long mykey = cand[i];
            int rank = 0;
            #pragma unroll 8
            for (int j = 0; j < Mr; ++j) rank += (cand[j] > mykey) ? 1 : 0;
            if (mykey != 0ull && rank < TOPK) ssel[rank] = mykey;
        }
    }
    __syncthreads();

    // ---- decode top-100: f64 ONCE per box -> LDS; f32 shadows are casts
    if (tid < TOPK) {
        unsigned long long key = ssel[tid];
        int valid = (key != 0ull);
        double bx[4] = {0.0, 0.0, 0.0, 0.0}, ar = 0.0;
        float sc = 0.f;
        if (valid) {
            int a = (int)(~(unsigned)key);
            float x = unmapf((unsigned)(key >> 32));
            sc = 1.0f / (1.0f + __expf(-x));
            float4 r4 = *(const float4*)(boxreg + ((size_t)b * A_N + a) * 4);
            float4 p4 = *(const float4*)(priors + (size_t)a * 4);
            dec64(r4, p4, bx, &ar);
        }
        sb0[tid] = bx[0]; sb1[tid] = bx[1]; sb2[tid] = bx[2]; sb3[tid] = bx[3];
        sarea[tid] = ar;
        fb0[tid] = (float)bx[0]; fb1[tid] = (float)bx[1];
        fb2[tid] = (float)bx[2]; fb3[tid] = (float)bx[3];
        farea[tid] = (float)ar;
        fscore[tid] = sc;
        svalid[tid] = valid;
    }
    __syncthreads();

    // ---- suppression bitmask: f32 screen (narrow window), cheap f64 recheck
    for (int tt = tid; tt < 2 * TOPK; tt += NTHM) {
        int i = tt >> 1, w = tt & 1;
        unsigned long long m = 0;
        if (svalid[i]) {
            float i0 = fb0[i], i1 = fb1[i], i2 = fb2[i], i3 = fb3[i], ia = farea[i];
            int jbase = w * 64;
            int jend = min(jbase + 64, TOPK);
            int jstart = (jbase > i + 1) ? jbase : (i + 1);
            for (int j = jstart; j < jend; ++j) {
                float tl0 = fmaxf(i0, fb0[j]);
                float tl1 = fmaxf(i1, fb1[j]);
                float br0 = fminf(i2, fb2[j]);
                float br1 = fminf(i3, fb3[j]);
                float wh0 = fmaxf(br0 - tl0, 0.0f);
                float wh1 = fmaxf(br1 - tl1, 0.0f);
                float inter = wh0 * wh1;
                float denom = (ia + farea[j]) - inter;
                bool sup = inter > 0.6004f * denom;
                bool amb = !sup && (inter > 0.5996f * denom) && (inter > 0.0f);
                if (amb) {   // rare; cheap: f64 boxes already in LDS (no exp!)
                    double tl0d = fmax(sb0[i], sb0[j]);
                    double tl1d = fmax(sb1[i], sb1[j]);
                    double br0d = fmin(sb2[i], sb2[j]);
                    double br1d = fmin(sb3[i], sb3[j]);
                    double wh0d = br0d - tl0d; if (wh0d < 0.0) wh0d = 0.0;
                    double wh1d = br1d - tl1d; if (wh1d < 0.0) wh1d = 0.0;
                    double interd = wh0d * wh1d;
                    double denomd = ((sarea[i] + sarea[j]) - interd) + 1e-9;
                    sup = interd > 0.6 * denomd;
                }
                if (sup) m |= 1ull << (j - jbase);
            }
        }
        supmask[i][w] = m;
    }
    __syncthreads();

    // ---- serial greedy scan over bitmasks (tid 0; loads pipeline well)
    if (tid == 0) {
        unsigned long long kp0 = ~0ull, kp1 = ~0ull;
        for (int i = 0; i < TOPK; ++i) {
            bool kb = (i < 64) ? ((kp0 >> i) & 1ull) : ((kp1 >> (i - 64)) & 1ull);
            if (kb && svalid[i]) { kp0 &= ~supmask[i][0]; kp1 &= ~supmask[i][1]; }
        }
        keepw[0] = kp0; keepw[1] = kp1;
    }
    __syncthreads();

    // ---- write 5 floats per slot
    if (tid < TOPK) {
        bool kb = (tid < 64) ? ((keepw[0] >> tid) & 1ull)
                             : ((keepw[1] >> (tid - 64)) & 1ull);
        bool kp = kb && (svalid[tid] != 0);
        size_t base = ((size_t)task * TOPK + tid) * 5;
        out[base + 0] = kp ? fb0[tid] : 0.0f;
        out[base + 1] = kp ? fb1[tid] : 0.0f;
        out[base + 2] = kp ? fb2[tid] : 0.0f;
        out[base + 3] = kp ? fb3[tid] : 0.0f;
        out[base + 4] = kp ? fscore[tid] : 0.0f;
    }
}

// ---- Standalone fallback (ws too small): validated 256-thread path ----
__global__ __launch_bounds__(NTHR) void ssd_nms_fallback(
    const float* __restrict__ logits,
    const float* __restrict__ boxreg,
    const float* __restrict__ priors,
    float* __restrict__ out)
{
    const int task = blockIdx.x;
    const int b = task / NCLS;
    const int c = task % NCLS;
    const int tid = threadIdx.x;

    __shared__ unsigned hist[2048];
    __shared__ unsigned wt4[4];
    __shared__ unsigned long long cand[CAND];
    __shared__ unsigned long long ssel[TOPK];
    __shared__ double sb0[TOPK], sb1[TOPK], sb2[TOPK], sb3[TOPK], sarea[TOPK];
    __shared__ float fb0[TOPK], fb1[TOPK], fb2[TOPK], fb3[TOPK];
    __shared__ float farea[TOPK], fscore[TOPK];
    __shared__ int svalid[TOPK];
    __shared__ unsigned long long supmask[TOPK][2];
    __shared__ unsigned long long keepw[2];
    __shared__ int scal[2];

    const float* lg = logits + ((size_t)b * A_N * C_N) + (c + 1);

    for (int k = tid; k < 2048; k += NTHR) hist[k] = 0;
    for (int i = tid; i < CAND; i += NTHR) cand[i] = 0ull;
    if (tid < TOPK) ssel[tid] = 0ull;
    if (tid == 0) { scal[0] = 0; scal[1] = 1; }
    __syncthreads();

    for (int a = tid; a < A_N; a += NTHR) {
        float x = lg[(size_t)a * C_N];
        if ((double)x > THR_LOGIT) atomicAdd(&hist[mapf(x) >> 21], 1u);
    }
    __syncthreads();
    {
        unsigned s = 0;
        #pragma unroll
        for (int k = 0; k < 8; ++k) s += hist[tid * 8 + k];
        unsigned incl = s;
        int lane = tid & 63;
        #pragma unroll
        for (int off = 1; off < 64; off <<= 1) {
            unsigned v = __shfl_down(incl, off);
            if (lane + off < 64) incl += v;
        }
        if (lane == 0) wt4[tid >> 6] = incl;
        __syncthreads();
        unsigned hi = 0;
        #pragma unroll
        for (int w = 0; w < 4; ++w) if (w > (tid >> 6)) hi += wt4[w];
        unsigned excl = hi + (incl - s);
        if (excl < TOPK && excl + s >= TOPK) {
            unsigned running = excl;
            #pragma unroll
            for (int k = 7; k >= 0; --k) {
                running += hist[tid * 8 + k];
                if (running >= TOPK) { scal[1] = (int)(((unsigned)(tid * 8 + k)) << 21); break; }
            }
        }
    }
    __syncthreads();
    const unsigned cutoff = (unsigned)scal[1];

    for (int a = tid; a < A_N; a += NTHR) {
        float x = lg[(size_t)a * C_N];
        if ((double)x > THR_LOGIT) {
            unsigned u = mapf(x);
            if (u >= cutoff) {
                int p = atomicAdd(&scal[0], 1);
                if (p < CAND) cand[p] = ((unsigned long long)u << 32) | (unsigned)(~(unsigned)a);
            }
        }
    }
    __syncthreads();
    const int M = min(scal[0], CAND);
    {
        int Mr = (M + 7) & ~7;
        for (int i = tid; i < Mr; i += NTHR) {
            unsigned long long mykey = cand[i];
            int rank = 0;
            for (int j = 0; j < Mr; ++j) rank += (cand[j] > mykey) ? 1 : 0;
            if (mykey != 0ull && rank < TOPK) ssel[rank] = mykey;
        }
    }
    __syncthreads();
    if (tid < TOPK) {
        unsigned long long key = ssel[tid];
        int valid = (key != 0ull);
        double bx[4] = {0.0, 0.0, 0.0, 0.0}, ar = 0.0;
        float sc = 0.f;
        if (valid) {
            int a = (int)(~(unsigned)key);
            float x = unmapf((unsigned)(key >> 32));
            sc = 1.0f / (1.0f + __expf(-x));
            float4 r4 = *(const float4*)(boxreg + ((size_t)b * A_N + a) * 4);
            float4 p4 = *(const float4*)(priors + (size_t)a * 4);
            dec64(r4, p4, bx, &ar);
        }
        sb0[tid] = bx[0]; sb1[tid] = bx[1]; sb2[tid] = bx[2]; sb3[tid] = bx[3];
        sarea[tid] = ar;
        fb0[tid] = (float)bx[0]; fb1[tid] = (float)bx[1];
        fb2[tid] = (float)bx[2]; fb3[tid] = (float)bx[3];
        farea[tid] = (float)ar; fscore[tid] = sc; svalid[tid] = valid;
    }
    __syncthreads();
    if (tid < 2 * TOPK) {
        int i = tid >> 1, w = tid & 1;
        unsigned long long m = 0;
        if (svalid[i]) {
            float i0=fb0[i], i1=fb1[i], i2=fb2[i], i3=fb3[i], ia=farea[i];
            int jbase = w * 64, jend = min(jbase + 64, TOPK);
            int jstart = (jbase > i + 1) ? jbase : (i + 1);
            for (int j = jstart; j < jend; ++j) {
                float tl0=fmaxf(i0,fb0[j]), tl1=fmaxf(i1,fb1[j]);
                float br0=fminf(i2,fb2[j]), br1=fminf(i3,fb3[j]);
                float wh0=fmaxf(br0-tl0,0.f), wh1=fmaxf(br1-tl1,0.f);
                float inter=wh0*wh1, denom=(ia+farea[j])-inter;
                bool sup = inter > 0.6004f*denom;
                bool amb = !sup && (inter > 0.5996f*denom) && (inter > 0.f);
                if (amb) {
                    double tl0d = fmax(sb0[i], sb0[j]);
                    double tl1d = fmax(sb1[i], sb1[j]);
                    double br0d = fmin(sb2[i], sb2[j]);
                    double br1d = fmin(sb3[i], sb3[j]);
                    double wh0d = br0d - tl0d; if (wh0d < 0.0) wh0d = 0.0;
                    double wh1d = br1d - tl1d; if (wh1d < 0.0) wh1d = 0.0;
                    double interd = wh0d * wh1d;
                    sup = interd > 0.6 * (((sarea[i] + sarea[j]) - interd) + 1e-9);
                }
                if (sup) m |= 1ull << (j - jbase);
            }
        }
        supmask[i][w] = m;
    }
    __syncthreads();
    if (tid == 0) {
        unsigned long long kp0 = ~0ull, kp1 = ~0ull;
        for (int i = 0; i < TOPK; ++i) {
            bool kb = (i < 64) ? ((kp0 >> i) & 1ull) : ((kp1 >> (i - 64)) & 1ull);
            if (kb && svalid[i]) { kp0 &= ~supmask[i][0]; kp1 &= ~supmask[i][1]; }
        }
        keepw[0] = kp0; keepw[1] = kp1;
    }
    __syncthreads();
    if (tid < TOPK) {
        bool kb = (tid < 64) ? ((keepw[0] >> tid) & 1ull)
                             : ((keepw[1] >> (tid - 64)) & 1ull);
        bool kp = kb && (svalid[tid] != 0);
        size_t base = ((size_t)task * TOPK + tid) * 5;
        out[base + 0] = kp ? fb0[tid] : 0.0f;
        out[base + 1] = kp ? fb1[tid] : 0.0f;
        out[base + 2] = kp ? fb2[tid] : 0.0f;
        out[base + 3] = kp ? fb3[tid] : 0.0f;
        out[base + 4] = kp ? fscore[tid] : 0.0f;
    }
}

extern "C" void kernel_launch(void* const* d_in, const int* in_sizes, int n_in,
                              void* d_out, int out_size, void* d_ws, size_t ws_size,
                              hipStream_t stream) {
    const float* logits = (const float*)d_in[0];
    const float* boxreg = (const float*)d_in[1];
    const float* priors = (const float*)d_in[2];
    float* out = (float*)d_out;

    const size_t cand_bytes  = (size_t)NTASK * CAND * sizeof(unsigned long long); // 10.49 MB
    const size_t count_bytes = (size_t)NTASK * CPAD * sizeof(unsigned);           // 160 KB
    if (ws_size >= cand_bytes + count_bytes) {
        unsigned long long* gcand = (unsigned long long*)d_ws;
        unsigned* gcountP = (unsigned*)((char*)d_ws + cand_bytes);
        hipMemsetAsync(gcountP, 0, count_bytes, stream);
        scatter_cand_kernel<<<dim3(B_N * NCH), dim3(NTHR), 0, stream>>>(
            logits, gcand, gcountP);
        ssd_nms_kernel<<<dim3(NTASK), dim3(NTHM), 0, stream>>>(
            logits, gcand, gcountP, boxreg, priors, out);
    } else {
        ssd_nms_fallback<<<dim3(NTASK), dim3(NTHR), 0, stream>>>(
            logits, boxreg, priors, out);
    }
}

// Round 21
// 81.564 us; speedup vs baseline: 1.9043x; 1.0059x over previous
//
#include <hip/hip_runtime.h>
#include <math.h>

#define A_N   8732
#define C_N   81
#define B_N   32
#define NCLS  80
#define NTASK (B_N * NCLS)
#define TOPK  100
#define NTHR  256            // scatter / standalone-fallback block size
#define NTHM  128            // main kernel block size
#define CAND  512
#define ACH   128                        // anchors per scatter chunk
#define NCH   ((A_N + ACH - 1) / ACH)    // 69
#define LCAP  16                         // LDS list slots per (block, task)
#define CPAD  16                         // gcount padding: 16 u32 = 64 B per task
#define THR_LOGIT (-0.8472978603872034)  // ln(3/7): sigmoid_f64(x)>0.3 <=> x>THR
#define XFIX  2.1f                       // optimistic gather threshold (mu~156)

// ---- LDS layout for main kernel: packed to 10.4 KB -> 15 blocks/CU (30 waves)
// region A (0..4096): hist[1024] (fallback only) OVERLAYS sb0..sarea+keepw
#define OFF_SB0    0        // double[100] -> 800
#define OFF_SB1    800
#define OFF_SB2    1600
#define OFF_SB3    2400
#define OFF_SAREA  3200     // -> 4000
#define OFF_KEEPW  4000     // u64[2] -> 4016
#define OFF_HIST   0        // unsigned[1024] -> 4096 (fallback path only)
// region B (4096..8192): cand u64[512] (dead after rank) OVERLAYS f32 shadows
#define OFF_CAND   4096     // -> 8192
#define OFF_FB0    4096     // float[100]
#define OFF_FB1    4496
#define OFF_FB2    4896
#define OFF_FB3    5296
#define OFF_FAREA  5696
#define OFF_FSC    6096
#define OFF_SVAL   6496     // int[100] -> 6896
// region C
#define OFF_SSEL   8192     // u64[100] -> 8992
#define OFF_SUP    8992     // u64[100][2] -> 10592
#define OFF_WT4    10592    // -> 10608
#define OFF_SCAL   10608    // -> 10616
#define SMEM_SZ    10624

__device__ __forceinline__ unsigned mapf(float x) {
    unsigned b = __float_as_uint(x);
    return b ^ ((b & 0x80000000u) ? 0xFFFFFFFFu : 0x80000000u);
}
__device__ __forceinline__ float unmapf(unsigned u) {
    unsigned b = (u & 0x80000000u) ? (u ^ 0x80000000u) : ~u;
    return __uint_as_float(b);
}

// Exact f64 decode (reference op order) from raw regression/prior values.
__device__ __forceinline__ void dec64(const float4 r4, const float4 p4,
                                      double* bx, double* area) {
    double ty = (double)r4.x / 10.0, tx = (double)r4.y / 10.0;
    double th = (double)r4.z / 5.0,  tw = (double)r4.w / 5.0;
    double cy = ty * (double)p4.z + (double)p4.x;
    double cx = tx * (double)p4.w + (double)p4.y;
    double hh = exp(th) * (double)p4.z;
    double ww = exp(tw) * (double)p4.w;
    bx[0] = cy - hh / 2.0; bx[1] = cx - ww / 2.0;
    bx[2] = cy + hh / 2.0; bx[3] = cx + ww / 2.0;
    double e0 = bx[2] - bx[0]; if (e0 < 0.0) e0 = 0.0;
    double e1 = bx[3] - bx[1]; if (e1 < 0.0) e1 = 0.0;
    *area = e0 * e1;
}

// ---- Kernel S: contiguous slab read + LDS-aggregated candidate scatter ----
__global__ __launch_bounds__(NTHR) void scatter_cand_kernel(
    const float* __restrict__ logits,            // (B, A, 81)
    unsigned long long* __restrict__ gcand,      // (NTASK, CAND) full sort keys
    unsigned* __restrict__ gcountP)              // (NTASK * CPAD) padded counters
{
    __shared__ unsigned long long llist[NCLS * LCAP];   // 10 KB
    __shared__ unsigned lcnt[NCLS];
    __shared__ unsigned sbase[NCLS];

    const int b  = blockIdx.x / NCH;
    const int ck = blockIdx.x % NCH;
    const int a0 = ck * ACH;
    const int an = min(ACH, A_N - a0);
    const int tid = threadIdx.x;

    for (int i = tid; i < NCLS; i += NTHR) lcnt[i] = 0;
    __syncthreads();

    const unsigned NE4 = (unsigned)(an * C_N) / 4u;     // exact (NE % 4 == 0)
    const float4* src4 = (const float4*)logits
                       + ((size_t)C_N * ((size_t)b * A_N + a0)) / 4;

    auto PROC = [&](float4 v, unsigned f) {
        float mx = fmaxf(fmaxf(v.x, v.y), fmaxf(v.z, v.w));
        if (mx < XFIX) return;                          // ~93% of quads skip
        unsigned e = f * 4u;
        float xs[4] = { v.x, v.y, v.z, v.w };
        #pragma unroll
        for (int k = 0; k < 4; ++k) {
            if (xs[k] >= XFIX) {
                unsigned rel = e + (unsigned)k;
                unsigned ar = rel / (unsigned)C_N;      // const-div (magic mul)
                unsigned ch = rel - ar * (unsigned)C_N;
                if (ch > 0) {
                    int t = (int)ch - 1;
                    unsigned a = (unsigned)a0 + ar;
                    unsigned long long key =
                        ((unsigned long long)mapf(xs[k]) << 32) | (unsigned)(~a);
                    unsigned pos = atomicAdd(&lcnt[t], 1u);
                    if (pos < LCAP) {
                        llist[t * LCAP + pos] = key;
                    } else {                             // ~never: direct append
                        int task = b * NCLS + t;
                        unsigned p = atomicAdd(&gcountP[task * CPAD], 1u);
                        if (p < CAND) gcand[(size_t)task * CAND + p] = key;
                    }
                }
            }
        }
    };

    unsigned f = tid;
    for (; f + 7u * NTHR < NE4; f += 8u * NTHR) {       // 8 loads in flight
        float4 v0 = src4[f];
        float4 v1 = src4[f + NTHR];
        float4 v2 = src4[f + 2u * NTHR];
        float4 v3 = src4[f + 3u * NTHR];
        float4 v4 = src4[f + 4u * NTHR];
        float4 v5 = src4[f + 5u * NTHR];
        float4 v6 = src4[f + 6u * NTHR];
        float4 v7 = src4[f + 7u * NTHR];
        PROC(v0, f);               PROC(v1, f + NTHR);
        PROC(v2, f + 2u * NTHR);   PROC(v3, f + 3u * NTHR);
        PROC(v4, f + 4u * NTHR);   PROC(v5, f + 5u * NTHR);
        PROC(v6, f + 6u * NTHR);   PROC(v7, f + 7u * NTHR);
    }
    for (; f < NE4; f += NTHR) PROC(src4[f], f);
    __syncthreads();

    if (tid < NCLS) {
        unsigned n = lcnt[tid]; if (n > LCAP) n = LCAP;
        sbase[tid] = n ? atomicAdd(&gcountP[(b * NCLS + tid) * CPAD], n) : 0u;
        lcnt[tid] = n;
    }
    __syncthreads();

    for (int i = tid; i < NCLS * LCAP; i += NTHR) {
        int t = i >> 4, s = i & (LCAP - 1);
        if ((unsigned)s < lcnt[t]) {
            unsigned dst = sbase[t] + (unsigned)s;
            if (dst < CAND)
                gcand[(size_t)(b * NCLS + t) * CAND + dst] = llist[i];
        }
    }
}

// ---- Kernel M: one task per 128-thread block; ~15 blocks/CU resident ----
__global__ __launch_bounds__(NTHM) void ssd_nms_kernel(
    const float* __restrict__ logits,
    const unsigned long long* __restrict__ gcand,
    const unsigned* __restrict__ gcountP,
    const float* __restrict__ boxreg,
    const float* __restrict__ priors,
    float* __restrict__ out)
{
    const int task = blockIdx.x;
    const int b = task / NCLS;
    const int c = task % NCLS;
    const int tid = threadIdx.x;

    __shared__ __align__(16) char smem[SMEM_SZ];
    unsigned* hist = (unsigned*)(smem + OFF_HIST);
    unsigned long long* cand = (unsigned long long*)(smem + OFF_CAND);
    unsigned long long* ssel = (unsigned long long*)(smem + OFF_SSEL);
    unsigned* wt4 = (unsigned*)(smem + OFF_WT4);
    int* scal = (int*)(smem + OFF_SCAL);
    double* sb0 = (double*)(smem + OFF_SB0);
    double* sb1 = (double*)(smem + OFF_SB1);
    double* sb2 = (double*)(smem + OFF_SB2);
    double* sb3 = (double*)(smem + OFF_SB3);
    double* sarea = (double*)(smem + OFF_SAREA);
    float* fb0 = (float*)(smem + OFF_FB0);
    float* fb1 = (float*)(smem + OFF_FB1);
    float* fb2 = (float*)(smem + OFF_FB2);
    float* fb3 = (float*)(smem + OFF_FB3);
    float* farea = (float*)(smem + OFF_FAREA);
    float* fscore = (float*)(smem + OFF_FSC);
    int* svalid = (int*)(smem + OFF_SVAL);
    unsigned long long (*supmask)[2] = (unsigned long long (*)[2])(smem + OFF_SUP);
    unsigned long long* keepw = (unsigned long long*)(smem + OFF_KEEPW);

    const float* lg = logits + ((size_t)b * A_N * C_N) + (c + 1);

    if (tid < TOPK) ssel[tid] = 0ull;
    if (tid == 0) { scal[0] = 0; scal[1] = 1; }

    const int count = (int)gcountP[task * CPAD];
    int M;
    if (count >= TOPK && count <= CAND) {
        // optimistic: keys already assembled by the scatter kernel
        M = count;
        const unsigned long long* lst = gcand + (size_t)task * CAND;
        for (int i = tid; i < M; i += NTHM) cand[i] = lst[i];
    } else {
        // fallback: full strided scan (rare / degenerate data), 1024-bin hist
        for (int k = tid; k < 1024; k += NTHM) hist[k] = 0;
        __syncthreads();
        for (int a = tid; a < A_N; a += NTHM) {
            float x = lg[(size_t)a * C_N];
            if ((double)x > THR_LOGIT) atomicAdd(&hist[mapf(x) >> 22], 1u);
        }
        __syncthreads();
        {
            unsigned s = 0;
            #pragma unroll
            for (int k = 0; k < 8; ++k) s += hist[tid * 8 + k];
            unsigned incl = s;
            int lane = tid & 63;
            #pragma unroll
            for (int off = 1; off < 64; off <<= 1) {
                unsigned v = __shfl_down(incl, off);
                if (lane + off < 64) incl += v;
            }
            if (lane == 0) wt4[tid >> 6] = incl;     // waves 0,1
            __syncthreads();
            unsigned hi = (tid < 64) ? wt4[1] : 0u;  // waves above mine
            unsigned excl = hi + (incl - s);
            if (excl < TOPK && excl + s >= TOPK) {
                unsigned running = excl;
                #pragma unroll
                for (int k = 7; k >= 0; --k) {
                    running += hist[tid * 8 + k];
                    if (running >= TOPK) { scal[1] = (int)(((unsigned)(tid * 8 + k)) << 22); break; }
                }
            }
        }
        __syncthreads();
        const unsigned cutoff = (unsigned)scal[1];
        for (int a = tid; a < A_N; a += NTHM) {
            float x = lg[(size_t)a * C_N];
            if ((double)x > THR_LOGIT) {
                unsigned u = mapf(x);
                if (u >= cutoff) {
                    int p = atomicAdd(&scal[0], 1);
                    if (p < CAND) cand[p] = ((unsigned long long)u << 32) | (unsigned)(~(unsigned)a);
                }
            }
        }
        __syncthreads();
        M = min(scal[0], CAND);
    }
    {
        int Mr = (M + 7) & ~7;
        for (int i = M + tid; i < Mr; i += NTHM) cand[i] = 0ull;
    }
    __syncthreads();

    // ---- exact rank via all-pairs (order-independent, LDS broadcast reads)
    {
        int Mr = (M + 7) & ~7;
        for (int i = tid; i < Mr; i += NTHM) {
            unsigned long long mykey = cand[i];
            int rank = 0;
            #pragma unroll 8
            for (int j = 0; j < Mr; ++j) rank += (cand[j] > mykey) ? 1 : 0;
            if (mykey != 0ull && rank < TOPK) ssel[rank] = mykey;
        }
    }
    __syncthreads();

    // ---- decode top-100: f64 ONCE per box -> LDS; f32 shadows are casts
    if (tid < TOPK) {
        unsigned long long key = ssel[tid];
        int valid = (key != 0ull);
        double bx[4] = {0.0, 0.0, 0.0, 0.0}, ar = 0.0;
        float sc = 0.f;
        if (valid) {
            int a = (int)(~(unsigned)key);
            float x = unmapf((unsigned)(key >> 32));
            sc = 1.0f / (1.0f + __expf(-x));
            float4 r4 = *(const float4*)(boxreg + ((size_t)b * A_N + a) * 4);
            float4 p4 = *(const float4*)(priors + (size_t)a * 4);
            dec64(r4, p4, bx, &ar);
        }
        sb0[tid] = bx[0]; sb1[tid] = bx[1]; sb2[tid] = bx[2]; sb3[tid] = bx[3];
        sarea[tid] = ar;
        fb0[tid] = (float)bx[0]; fb1[tid] = (float)bx[1];
        fb2[tid] = (float)bx[2]; fb3[tid] = (float)bx[3];
        farea[tid] = (float)ar;
        fscore[tid] = sc;
        svalid[tid] = valid;
    }
    __syncthreads();

    // ---- suppression bitmask: f32 screen (narrow window), cheap f64 recheck
    for (int tt = tid; tt < 2 * TOPK; tt += NTHM) {
        int i = tt >> 1, w = tt & 1;
        unsigned long long m = 0;
        if (svalid[i]) {
            float i0 = fb0[i], i1 = fb1[i], i2 = fb2[i], i3 = fb3[i], ia = farea[i];
            int jbase = w * 64;
            int jend = min(jbase + 64, TOPK);
            int jstart = (jbase > i + 1) ? jbase : (i + 1);
            for (int j = jstart; j < jend; ++j) {
                float tl0 = fmaxf(i0, fb0[j]);
                float tl1 = fmaxf(i1, fb1[j]);
                float br0 = fminf(i2, fb2[j]);
                float br1 = fminf(i3, fb3[j]);
                float wh0 = fmaxf(br0 - tl0, 0.0f);
                float wh1 = fmaxf(br1 - tl1, 0.0f);
                float inter = wh0 * wh1;
                float denom = (ia + farea[j]) - inter;
                bool sup = inter > 0.6004f * denom;
                bool amb = !sup && (inter > 0.5996f * denom) && (inter > 0.0f);
                if (amb) {   // rare; cheap: f64 boxes already in LDS (no exp!)
                    double tl0d = fmax(sb0[i], sb0[j]);
                    double tl1d = fmax(sb1[i], sb1[j]);
                    double br0d = fmin(sb2[i], sb2[j]);
                    double br1d = fmin(sb3[i], sb3[j]);
                    double wh0d = br0d - tl0d; if (wh0d < 0.0) wh0d = 0.0;
                    double wh1d = br1d - tl1d; if (wh1d < 0.0) wh1d = 0.0;
                    double interd = wh0d * wh1d;
                    double denomd = ((sarea[i] + sarea[j]) - interd) + 1e-9;
                    sup = interd > 0.6 * denomd;
                }
                if (sup) m |= 1ull << (j - jbase);
            }
        }
        supmask[i][w] = m;
    }
    __syncthreads();

    // ---- serial greedy scan over bitmasks (tid 0; loads pipeline well)
    if (tid == 0) {
        unsigned long long kp0 = ~0ull, kp1 = ~0ull;
        for (int i = 0; i < TOPK; ++i) {
            bool kb = (i < 64) ? ((kp0 >> i) & 1ull) : ((kp1 >> (i - 64)) & 1ull);
            if (kb && svalid[i]) { kp0 &= ~supmask[i][0]; kp1 &= ~supmask[i][1]; }
        }
        keepw[0] = kp0; keepw[1] = kp1;
    }
    __syncthreads();

    // ---- write 5 floats per slot
    if (tid < TOPK) {
        bool kb = (tid < 64) ? ((keepw[0] >> tid) & 1ull)
                             : ((keepw[1] >> (tid - 64)) & 1ull);
        bool kp = kb && (svalid[tid] != 0);
        size_t base = ((size_t)task * TOPK + tid) * 5;
        out[base + 0] = kp ? fb0[tid] : 0.0f;
        out[base + 1] = kp ? fb1[tid] : 0.0f;
        out[base + 2] = kp ? fb2[tid] : 0.0f;
        out[base + 3] = kp ? fb3[tid] : 0.0f;
        out[base + 4] = kp ? fscore[tid] : 0.0f;
    }
}

// ---- Standalone fallback (ws too small): validated 256-thread path ----
__global__ __launch_bounds__(NTHR) void ssd_nms_fallback(
    const float* __restrict__ logits,
    const float* __restrict__ boxreg,
    const float* __restrict__ priors,
    float* __restrict__ out)
{
    const int task = blockIdx.x;
    const int b = task / NCLS;
    const int c = task % NCLS;
    const int tid = threadIdx.x;

    __shared__ unsigned hist[2048];
    __shared__ unsigned wt4[4];
    __shared__ unsigned long long cand[CAND];
    __shared__ unsigned long long ssel[TOPK];
    __shared__ double sb0[TOPK], sb1[TOPK], sb2[TOPK], sb3[TOPK], sarea[TOPK];
    __shared__ float fb0[TOPK], fb1[TOPK], fb2[TOPK], fb3[TOPK];
    __shared__ float farea[TOPK], fscore[TOPK];
    __shared__ int svalid[TOPK];
    __shared__ unsigned long long supmask[TOPK][2];
    __shared__ unsigned long long keepw[2];
    __shared__ int scal[2];

    const float* lg = logits + ((size_t)b * A_N * C_N) + (c + 1);

    for (int k = tid; k < 2048; k += NTHR) hist[k] = 0;
    for (int i = tid; i < CAND; i += NTHR) cand[i] = 0ull;
    if (tid < TOPK) ssel[tid] = 0ull;
    if (tid == 0) { scal[0] = 0; scal[1] = 1; }
    __syncthreads();

    for (int a = tid; a < A_N; a += NTHR) {
        float x = lg[(size_t)a * C_N];
        if ((double)x > THR_LOGIT) atomicAdd(&hist[mapf(x) >> 21], 1u);
    }
    __syncthreads();
    {
        unsigned s = 0;
        #pragma unroll
        for (int k = 0; k < 8; ++k) s += hist[tid * 8 + k];
        unsigned incl = s;
        int lane = tid & 63;
        #pragma unroll
        for (int off = 1; off < 64; off <<= 1) {
            unsigned v = __shfl_down(incl, off);
            if (lane + off < 64) incl += v;
        }
        if (lane == 0) wt4[tid >> 6] = incl;
        __syncthreads();
        unsigned hi = 0;
        #pragma unroll
        for (int w = 0; w < 4; ++w) if (w > (tid >> 6)) hi += wt4[w];
        unsigned excl = hi + (incl - s);
        if (excl < TOPK && excl + s >= TOPK) {
            unsigned running = excl;
            #pragma unroll
            for (int k = 7; k >= 0; --k) {
                running += hist[tid * 8 + k];
                if (running >= TOPK) { scal[1] = (int)(((unsigned)(tid * 8 + k)) << 21); break; }
            }
        }
    }
    __syncthreads();
    const unsigned cutoff = (unsigned)scal[1];

    for (int a = tid; a < A_N; a += NTHR) {
        float x = lg[(size_t)a * C_N];
        if ((double)x > THR_LOGIT) {
            unsigned u = mapf(x);
            if (u >= cutoff) {
                int p = atomicAdd(&scal[0], 1);
                if (p < CAND) cand[p] = ((unsigned long long)u << 32) | (unsigned)(~(unsigned)a);
            }
        }
    }
    __syncthreads();
    const int M = min(scal[0], CAND);
    {
        int Mr = (M + 7) & ~7;
        for (int i = tid; i < Mr; i += NTHR) {
            unsigned long long mykey = cand[i];
            int rank = 0;
            for (int j = 0; j < Mr; ++j) rank += (cand[j] > mykey) ? 1 : 0;
            if (mykey != 0ull && rank < TOPK) ssel[rank] = mykey;
        }
    }
    __syncthreads();
    if (tid < TOPK) {
        unsigned long long key = ssel[tid];
        int valid = (key != 0ull);
        double bx[4] = {0.0, 0.0, 0.0, 0.0}, ar = 0.0;
        float sc = 0.f;
        if (valid) {
            int a = (int)(~(unsigned)key);
            float x = unmapf((unsigned)(key >> 32));
            sc = 1.0f / (1.0f + __expf(-x));
            float4 r4 = *(const float4*)(boxreg + ((size_t)b * A_N + a) * 4);
            float4 p4 = *(const float4*)(priors + (size_t)a * 4);
            dec64(r4, p4, bx, &ar);
        }
        sb0[tid] = bx[0]; sb1[tid] = bx[1]; sb2[tid] = bx[2]; sb3[tid] = bx[3];
        sarea[tid] = ar;
        fb0[tid] = (float)bx[0]; fb1[tid] = (float)bx[1];
        fb2[tid] = (float)bx[2]; fb3[tid] = (float)bx[3];
        farea[tid] = (float)ar; fscore[tid] = sc; svalid[tid] = valid;
    }
    __syncthreads();
    if (tid < 2 * TOPK) {
        int i = tid >> 1, w = tid & 1;
        unsigned long long m = 0;
        if (svalid[i]) {
            float i0=fb0[i], i1=fb1[i], i2=fb2[i], i3=fb3[i], ia=farea[i];
            int jbase = w * 64, jend = min(jbase + 64, TOPK);
            int jstart = (jbase > i + 1) ? jbase : (i + 1);
            for (int j = jstart; j < jend; ++j) {
                float tl0=fmaxf(i0,fb0[j]), tl1=fmaxf(i1,fb1[j]);
                float br0=fminf(i2,fb2[j]), br1=fminf(i3,fb3[j]);
                float wh0=fmaxf(br0-tl0,0.f), wh1=fmaxf(br1-tl1,0.f);
                float inter=wh0*wh1, denom=(ia+farea[j])-inter;
                bool sup = inter > 0.6004f*denom;
                bool amb = !sup && (inter > 0.5996f*denom) && (inter > 0.f);
                if (amb) {
                    double tl0d = fmax(sb0[i], sb0[j]);
                    double tl1d = fmax(sb1[i], sb1[j]);
                    double br0d = fmin(sb2[i], sb2[j]);
                    double br1d = fmin(sb3[i], sb3[j]);
                    double wh0d = br0d - tl0d; if (wh0d < 0.0) wh0d = 0.0;
                    double wh1d = br1d - tl1d; if (wh1d < 0.0) wh1d = 0.0;
                    double interd = wh0d * wh1d;
                    sup = interd > 0.6 * (((sarea[i] + sarea[j]) - interd) + 1e-9);
                }
                if (sup) m |= 1ull << (j - jbase);
            }
        }
        supmask[i][w] = m;
    }
    __syncthreads();
    if (tid == 0) {
        unsigned long long kp0 = ~0ull, kp1 = ~0ull;
        for (int i = 0; i < TOPK; ++i) {
            bool kb = (i < 64) ? ((kp0 >> i) & 1ull) : ((kp1 >> (i - 64)) & 1ull);
            if (kb && svalid[i]) { kp0 &= ~supmask[i][0]; kp1 &= ~supmask[i][1]; }
        }
        keepw[0] = kp0; keepw[1] = kp1;
    }
    __syncthreads();
    if (tid < TOPK) {
        bool kb = (tid < 64) ? ((keepw[0] >> tid) & 1ull)
                             : ((keepw[1] >> (tid - 64)) & 1ull);
        bool kp = kb && (svalid[tid] != 0);
        size_t base = ((size_t)task * TOPK + tid) * 5;
        out[base + 0] = kp ? fb0[tid] : 0.0f;
        out[base + 1] = kp ? fb1[tid] : 0.0f;
        out[base + 2] = kp ? fb2[tid] : 0.0f;
        out[base + 3] = kp ? fb3[tid] : 0.0f;
        out[base + 4] = kp ? fscore[tid] : 0.0f;
    }
}

extern "C" void kernel_launch(void* const* d_in, const int* in_sizes, int n_in,
                              void* d_out, int out_size, void* d_ws, size_t ws_size,
                              hipStream_t stream) {
    const float* logits = (const float*)d_in[0];
    const float* boxreg = (const float*)d_in[1];
    const float* priors = (const float*)d_in[2];
    float* out = (float*)d_out;

    const size_t cand_bytes  = (size_t)NTASK * CAND * sizeof(unsigned long long); // 10.49 MB
    const size_t count_bytes = (size_t)NTASK * CPAD * sizeof(unsigned);           // 160 KB
    if (ws_size >= cand_bytes + count_bytes) {
        unsigned long long* gcand = (unsigned long long*)d_ws;
        unsigned* gcountP = (unsigned*)((char*)d_ws + cand_bytes);
        hipMemsetAsync(gcountP, 0, count_bytes, stream);
        scatter_cand_kernel<<<dim3(B_N * NCH), dim3(NTHR), 0, stream>>>(
            logits, gcand, gcountP);
        ssd_nms_kernel<<<dim3(NTASK), dim3(NTHM), 0, stream>>>(
            logits, gcand, gcountP, boxreg, priors, out);
    } else {
        ssd_nms_fallback<<<dim3(NTASK), dim3(NTHR), 0, stream>>>(
            logits, boxreg, priors, out);
    }
}